// Round 11
// baseline (603.184 us; speedup 1.0000x reference)
//
#include <hip/hip_runtime.h>
#include <math.h>

#define TT 2048

typedef __attribute__((ext_vector_type(8))) short bfrag;   // 8 bf16 in 4 VGPRs
typedef __attribute__((ext_vector_type(4))) float facc;    // 4 fp32 acc

#define NEG_BIG (-1.0e30f)

typedef __attribute__((address_space(1))) const void gas_void;
typedef __attribute__((address_space(3))) void las_void;

__device__ __forceinline__ void gl_lds16(const void* g, void* l) {
    __builtin_amdgcn_global_load_lds((gas_void*)g, (las_void*)l, 16, 0, 0);
}

__device__ __forceinline__ unsigned short f2b(float f) {
    union { float f; unsigned int i; } v; v.f = f;
    unsigned int b = v.i;
    return (unsigned short)((b + 0x7FFFu + ((b >> 16) & 1u)) >> 16);  // RNE
}
__device__ __forceinline__ float b2f(unsigned short s) {
    union { unsigned int i; float f; } u; u.i = ((unsigned int)s) << 16; return u.f;
}
__device__ __forceinline__ void cvt8_f32(const float* __restrict__ p, unsigned short* d) {
    float4 lo = *(const float4*)p, hi = *(const float4*)(p + 4);
    d[0] = f2b(lo.x); d[1] = f2b(lo.y); d[2] = f2b(lo.z); d[3] = f2b(lo.w);
    d[4] = f2b(hi.x); d[5] = f2b(hi.y); d[6] = f2b(hi.z); d[7] = f2b(hi.w);
}

// ---------------------------------------------------------------------------
// Merged: fp32->bf16 convert of x (blocks 0..8191) + RoPE trig table
// (blocks 8192..8703). Per-thread code identical to the measured k_cvt/k_trig.
// ---------------------------------------------------------------------------
__global__ __launch_bounds__(256) void k_cvt_trig(const float* __restrict__ in,
                                                  unsigned short* __restrict__ out,
                                                  float2* __restrict__ tab,
                                                  const int* __restrict__ posPtr) {
    int bi = blockIdx.x;
    if (bi < 8192) {
        int c = bi * 256 + threadIdx.x;          // n8 = 2097152 exact
        unsigned short t[8];
        cvt8_f32(in + (size_t)c * 8, t);
        *(uint4*)(out + (size_t)c * 8) = *(const uint4*)t;
    } else {
        int tid = (bi - 8192) * 256 + threadIdx.x;   // 131072 total
        int i1 = tid & 63, t = tid >> 6;
        float p = (float)(*posPtr + t);
        float f = exp2f(-(float)i1 * 0.20762050595278f);
        float th = p * f;
        tab[tid] = make_float2(cosf(th), sinf(th));
    }
}

// ---------------------------------------------------------------------------
// Merged weight transpose+convert: all four W (2048 x N fp32) -> WT
// (N x 2048 bf16) in one launch. Flat decode:
//   [0,1024):    Wq -> WqT   (N=2048, bx=i&31, by=i>>5)
//   [1024,1280): Wk -> WkvT  (N=512,  bx=j&7,  by=j>>3)
//   [1280,1536): Wv -> WkvT+512*2048
//   [1536,2560): Wo -> WoT
// Inner code identical to the measured k_wt.
// ---------------------------------------------------------------------------
__global__ __launch_bounds__(256) void k_wt_all(const float* __restrict__ Wq,
                                                const float* __restrict__ Wk,
                                                const float* __restrict__ Wv,
                                                const float* __restrict__ Wo,
                                                unsigned short* __restrict__ WqT,
                                                unsigned short* __restrict__ WkvT,
                                                unsigned short* __restrict__ WoT) {
    __shared__ alignas(16) unsigned short tile[64][72];
    int i = blockIdx.x;
    const float* W; unsigned short* WT; int N, bx, by;
    if (i < 1024)      { W = Wq; WT = WqT; N = 2048; bx = i & 31; by = i >> 5; }
    else if (i < 1280) { int j = i - 1024; W = Wk; WT = WkvT; N = 512; bx = j & 7; by = j >> 3; }
    else if (i < 1536) { int j = i - 1280; W = Wv; WT = WkvT + (size_t)512 * 2048; N = 512; bx = j & 7; by = j >> 3; }
    else               { int j = i - 1536; W = Wo; WT = WoT; N = 2048; bx = j & 31; by = j >> 5; }
    int r0 = by * 64, c0 = bx * 64;
    int tid = threadIdx.x;
    for (int k = 0; k < 2; ++k) {
        int c = tid + k * 256;
        int row = c >> 3, c8 = (c & 7) * 8;
        unsigned short t[8];
        cvt8_f32(W + (size_t)(r0 + row) * N + c0 + c8, t);
        *(uint4*)&tile[row][c8] = *(const uint4*)t;
    }
    __syncthreads();
    for (int k = 0; k < 2; ++k) {
        int c = tid + k * 256;
        int col = c >> 3, r8 = (c & 7) * 8;
        unsigned short t[8];
        for (int j = 0; j < 8; ++j) t[j] = tile[r8 + j][col];
        *(uint4*)(WT + (size_t)(c0 + col) * 2048 + r0 + r8) = *(const uint4*)t;
    }
}

// ---------------------------------------------------------------------------
// Merged post-QKV pass: rope-Q (blocks [0,16384)), rope-K ([16384,20480)),
// V-transpose ([20480,21504)). rope writes cols <2560 of QKV; vt reads cols
// >=2560 -> disjoint, same-launch-safe. Inner code identical to measured
// k_rope / k_vt.
// ---------------------------------------------------------------------------
__global__ __launch_bounds__(256) void k_postq(unsigned short* __restrict__ QKV,
                                               unsigned short* __restrict__ VbT,
                                               const float2* __restrict__ tab) {
    __shared__ alignas(16) unsigned short tile[64][72];
    int bi = blockIdx.x;
    if (bi < 20480) {
        // rope: Q part (lognh=4, base QKV) or K part (lognh=2, base QKV+2048)
        unsigned short* X; int lognh, tid;
        if (bi < 16384) { X = QKV;        lognh = 4; tid = bi * 256 + threadIdx.x; }
        else            { X = QKV + 2048; lognh = 2; tid = (bi - 16384) * 256 + threadIdx.x; }
        int d2 = tid & 31;
        int nh = 1 << lognh;
        int h = (tid >> 5) & (nh - 1);
        int row = tid >> (5 + lognh);
        int t = row & (TT - 1);
        size_t base = (size_t)row * 3072 + h * 128 + d2 * 2;
        unsigned int ua = *(const unsigned int*)(X + base);
        unsigned int ub = *(const unsigned int*)(X + base + 64);
        float x1a = b2f((unsigned short)(ua & 0xffff));
        float x1b = b2f((unsigned short)(ua >> 16));
        float x2a = b2f((unsigned short)(ub & 0xffff));
        float x2b = b2f((unsigned short)(ub >> 16));
        float2 cs1 = tab[t * 64 + d2];
        float2 cs2 = tab[t * 64 + d2 + 32];
        unsigned int o1 = (unsigned int)f2b(x1a * cs1.x - x2a * cs1.y)
                        | ((unsigned int)f2b(x1b * cs1.x - x2b * cs1.y) << 16);
        unsigned int o2 = (unsigned int)f2b(x2a * cs2.x + x1a * cs2.y)
                        | ((unsigned int)f2b(x2b * cs2.x + x1b * cs2.y) << 16);
        *(unsigned int*)(X + base)      = o1;
        *(unsigned int*)(X + base + 64) = o2;
    } else {
        // V transpose: QKV cols 2560..3071 -> VbT (512 x 8192)
        int j = bi - 20480;
        int r0 = (j >> 3) * 64, c0 = (j & 7) * 64;
        int tid = threadIdx.x;
        for (int k = 0; k < 2; ++k) {
            int c = tid + k * 256;
            int row = c >> 3, c8 = (c & 7) * 8;
            *(uint4*)&tile[row][c8] =
                *(const uint4*)(QKV + (size_t)(r0 + row) * 3072 + 2560 + c0 + c8);
        }
        __syncthreads();
        for (int k = 0; k < 2; ++k) {
            int c = tid + k * 256;
            int col = c >> 3, r8 = (c & 7) * 8;
            unsigned short t[8];
            for (int jj = 0; jj < 8; ++jj) t[jj] = tile[r8 + jj][col];
            *(uint4*)(VbT + (size_t)(c0 + col) * 8192 + r0 + r8) = *(const uint4*)t;
        }
    }
}

// ---------------------------------------------------------------------------
// 2-phase double-buffered m97 GEMM, BK templated for the co-residency A/B:
//   BK=64 (control, round-6/7 winner): 64 KB LDS -> 2 blocks/CU, 32 barriers
//   BK=32 (experiment): 32 KB LDS -> 4-5 blocks/CU (drain hidden by more
//          co-resident blocks), 64 barriers. Round-4's BK=64 win was
//          SINGLE-buffered; 2-phase changes the tradeoff.
// Both use linear block mapping + the locked XOR chunk swizzle.
// ---------------------------------------------------------------------------
template <int BK>
__global__ __launch_bounds__(256) void k_gemm2ph(const unsigned short* __restrict__ A,
                                                 const unsigned short* __restrict__ Bt,
                                                 void* __restrict__ Cmat,
                                                 int M, int N, int K, int outF) {
    __shared__ union SM {
        struct { unsigned short A[2][128][BK]; unsigned short B[2][128][BK]; } s;
        unsigned short ct[32][136];
        float          ctf[32][136];
    } sm;
    int tid = threadIdx.x;
    int w = tid >> 6, lane = tid & 63, quad = lane >> 4, l15 = lane & 15;
    int m0 = blockIdx.y * 128, n0 = blockIdx.x * 128;
    int wm = (w >> 1) * 64, wn = (w & 1) * 64;

    facc acc[4][4];
#pragma unroll
    for (int mi = 0; mi < 4; ++mi)
#pragma unroll
        for (int ni = 0; ni < 4; ++ni)
#pragma unroll
            for (int r = 0; r < 4; ++r) acc[mi][ni][r] = 0.f;

    if constexpr (BK == 64) {
        int srow   = lane >> 3;                 // 0..7
        int schunk = (lane & 7) ^ (lane >> 3);  // inverse-swizzled source chunk

        auto stage = [&](int bb, int k0) {
#pragma unroll
            for (int i = 0; i < 4; ++i) {
                int row = w * 32 + i * 8;
                gl_lds16(A  + (size_t)(m0 + row + srow) * K + k0 + schunk * 8, &sm.s.A[bb][row][0]);
                gl_lds16(Bt + (size_t)(n0 + row + srow) * K + k0 + schunk * 8, &sm.s.B[bb][row][0]);
            }
        };

        int NT = K >> 6;
        stage(0, 0);
        __syncthreads();

        for (int t = 0; t < NT; ++t) {
            int cur = t & 1;
            if (t + 1 < NT) stage(cur ^ 1, (t + 1) * 64);

            bfrag af[4][2], bf[4][2];
#pragma unroll
            for (int mi = 0; mi < 4; ++mi)
#pragma unroll
                for (int kc = 0; kc < 2; ++kc)
                    af[mi][kc] = *(const bfrag*)&sm.s.A[cur][wm + mi * 16 + l15][((kc * 4 + quad) ^ (l15 & 7)) * 8];
#pragma unroll
            for (int ni = 0; ni < 4; ++ni)
#pragma unroll
                for (int kc = 0; kc < 2; ++kc)
                    bf[ni][kc] = *(const bfrag*)&sm.s.B[cur][wn + ni * 16 + l15][((kc * 4 + quad) ^ (l15 & 7)) * 8];
#pragma unroll
            for (int kc = 0; kc < 2; ++kc)
#pragma unroll
                for (int mi = 0; mi < 4; ++mi)
#pragma unroll
                    for (int ni = 0; ni < 4; ++ni)
                        acc[mi][ni] = __builtin_amdgcn_mfma_f32_16x16x32_bf16(af[mi][kc], bf[ni][kc], acc[mi][ni], 0, 0, 0);

            __syncthreads();
        }
    } else {
        // BK=32 (round-4 proven staging/swizzle + dbuf + single barrier)
        int srow   = lane >> 2;                       // 0..15
        int schunk = (lane & 3) ^ ((lane >> 3) & 3);  // 2-bit XOR chunk
        int rslot  = (quad ^ ((l15 >> 1) & 3)) * 8;

        auto stage = [&](int bb, int k0) {
#pragma unroll
            for (int j = 0; j < 2; ++j) {
                int row = w * 32 + j * 16;
                gl_lds16(A  + (size_t)(m0 + row + srow) * K + k0 + schunk * 8, &sm.s.A[bb][row][0]);
                gl_lds16(Bt + (size_t)(n0 + row + srow) * K + k0 + schunk * 8, &sm.s.B[bb][row][0]);
            }
        };

        int NT = K >> 5;
        stage(0, 0);
        __syncthreads();

        for (int t = 0; t < NT; ++t) {
            int cur = t & 1;
            if (t + 1 < NT) stage(cur ^ 1, (t + 1) * 32);

            bfrag af[4], bf[4];
#pragma unroll
            for (int mi = 0; mi < 4; ++mi) af[mi] = *(const bfrag*)&sm.s.A[cur][wm + mi * 16 + l15][rslot];
#pragma unroll
            for (int ni = 0; ni < 4; ++ni) bf[ni] = *(const bfrag*)&sm.s.B[cur][wn + ni * 16 + l15][rslot];
#pragma unroll
            for (int mi = 0; mi < 4; ++mi)
#pragma unroll
                for (int ni = 0; ni < 4; ++ni)
                    acc[mi][ni] = __builtin_amdgcn_mfma_f32_16x16x32_bf16(af[mi], bf[ni], acc[mi][ni], 0, 0, 0);

            __syncthreads();
        }
    }

    // epilogue: 4 rounds; round t stages every wave's mi=t subtile (32x128)
#pragma unroll
    for (int t = 0; t < 4; ++t) {
        __syncthreads();
#pragma unroll
        for (int ni = 0; ni < 4; ++ni)
#pragma unroll
            for (int r = 0; r < 4; ++r) {
                int lr = (w >> 1) * 16 + quad * 4 + r;
                int lc = wn + ni * 16 + l15;
                if (outF) sm.ctf[lr][lc] = acc[t][ni][r];
                else      sm.ct [lr][lc] = f2b(acc[t][ni][r]);
            }
        __syncthreads();
        if (outF) {
#pragma unroll
            for (int i = 0; i < 4; ++i) {
                int cc = tid + i * 256;
                int lr = cc >> 5, c4 = (cc & 31) * 4;
                int grow = m0 + (lr >> 4) * 64 + t * 16 + (lr & 15);
                *(float4*)((float*)Cmat + (size_t)grow * N + n0 + c4) =
                    *(const float4*)&sm.ctf[lr][c4];
            }
        } else {
#pragma unroll
            for (int i = 0; i < 2; ++i) {
                int cc = tid + i * 256;
                int lr = cc >> 4, c8 = (cc & 15) * 8;
                int grow = m0 + (lr >> 4) * 64 + t * 16 + (lr & 15);
                *(uint4*)((unsigned short*)Cmat + (size_t)grow * N + n0 + c8) =
                    *(const uint4*)&sm.ct[lr][c8];
            }
        }
    }
}

// ---------------------------------------------------------------------------
// Flash attention, causal, GQA (round-7/10 measured-good config, unchanged):
// 512 threads, QBLK=128, paired q-tiles (i, 15-i); double-buffered K/V LDS,
// one barrier per K-step, register prefetch post-barrier; inactive-tile
// skip; interior fast path; T13 defer-max THR=8; swapped QK^T softmax.
// ---------------------------------------------------------------------------
__device__ __forceinline__ void flash_pass(
    int qbase, int b, int h, int kvh,
    const unsigned short* __restrict__ QKV,
    const unsigned short* __restrict__ VbT,
    unsigned short* __restrict__ att,
    unsigned short (&Ks)[2][32][136],
    unsigned short (&Vt)[2][128][40],
    unsigned short (&Pt)[8][16][40]) {

    int tid = threadIdx.x;
    int w = tid >> 6, lane = tid & 63, quad = lane >> 4, l15 = lane & 15;

    bfrag qf[4];
    {
        size_t qrow = (size_t)(b * TT + qbase + w * 16 + l15);
        for (int kc = 0; kc < 4; ++kc)
            qf[kc] = *(const bfrag*)(QKV + qrow * 3072 + h * 128 + kc * 32 + quad * 8);
    }

    float mreg = NEG_BIG, lreg = 0.f;      // state for q = qgmin + l15
    facc o[8];
#pragma unroll
    for (int nb2 = 0; nb2 < 8; ++nb2)
#pragma unroll
        for (int r = 0; r < 4; ++r) o[nb2][r] = 0.f;

    int krow = tid >> 4, d8 = (tid & 15) * 8;
    int vd = tid >> 2, tc = (tid & 3) * 8;
    const unsigned short* Kg = QKV + (size_t)(b * TT) * 3072 + 2048 + kvh * 128;
    const unsigned short* Vg = VbT + (size_t)(kvh * 128 + vd) * 8192 + b * TT;

    const float sc = 0.08838834764831845f;   // 1/sqrt(128)
    int kmax = qbase + 128;
    int nt = kmax >> 5;
    int qgmin = qbase + w * 16;
    int myq = qgmin + l15;                   // this lane's q-row

    uint4 rk = *(const uint4*)(Kg + (size_t)krow * 3072 + d8);
    uint4 rv = *(const uint4*)(Vg + tc);

    for (int t = 0; t < nt; ++t) {
        int cur = t & 1;
        int k0 = t * 32;
        *(uint4*)&Ks[cur][krow][d8] = rk;
        *(uint4*)&Vt[cur][vd][tc]   = rv;
        __syncthreads();

        if (t + 1 < nt) {
            int k0n = k0 + 32;
            rk = *(const uint4*)(Kg + (size_t)(k0n + krow) * 3072 + d8);
            rv = *(const uint4*)(Vg + k0n + tc);
        }

        if (k0 > qgmin + 15) continue;       // fully-masked tile for this wave

        // swapped QK^T: A = K-frag, B = Q-frag -> D[k][q], q = l15
        facc s[2];
#pragma unroll
        for (int nb = 0; nb < 2; ++nb) {
#pragma unroll
            for (int r = 0; r < 4; ++r) s[nb][r] = 0.f;
#pragma unroll
            for (int kc = 0; kc < 4; ++kc) {
                bfrag kf = *(const bfrag*)&Ks[cur][nb * 16 + l15][kc * 32 + quad * 8];
                s[nb] = __builtin_amdgcn_mfma_f32_16x16x32_bf16(kf, qf[kc], s[nb], 0, 0, 0);
            }
        }

        bool fullT = (k0 + 31) <= qgmin;
        float v[2][4];
        if (fullT) {
#pragma unroll
            for (int nb = 0; nb < 2; ++nb)
#pragma unroll
                for (int r = 0; r < 4; ++r) v[nb][r] = s[nb][r] * sc;
        } else {
#pragma unroll
            for (int nb = 0; nb < 2; ++nb)
#pragma unroll
                for (int r = 0; r < 4; ++r) {
                    int kg = k0 + nb * 16 + quad * 4 + r;
                    v[nb][r] = (kg > myq) ? NEG_BIG : s[nb][r] * sc;
                }
        }

        // row max: 7 local fmax + 2-step fold
        float mx = fmaxf(fmaxf(fmaxf(v[0][0], v[0][1]), fmaxf(v[0][2], v[0][3])),
                         fmaxf(fmaxf(v[1][0], v[1][1]), fmaxf(v[1][2], v[1][3])));
        mx = fmaxf(mx, __shfl_xor(mx, 16, 64));
        mx = fmaxf(mx, __shfl_xor(mx, 32, 64));

        bool need = (mx > mreg + 8.f);       // T13 defer-max, THR=8
        float mnew = need ? mx : mreg;
        float alpha = need ? __expf(mreg - mnew) : 1.f;

        float p[2][4];
        float psum = 0.f;
#pragma unroll
        for (int nb = 0; nb < 2; ++nb)
#pragma unroll
            for (int r = 0; r < 4; ++r) {
                p[nb][r] = __expf(v[nb][r] - mnew);   // exp(-huge)=0 for masked
                psum += p[nb][r];
            }
        psum += __shfl_xor(psum, 16, 64);
        psum += __shfl_xor(psum, 32, 64);
        lreg = lreg * alpha + psum;
        mreg = mnew;

        // P -> LDS: lane writes 4 contiguous k per nb (8B each)
#pragma unroll
        for (int nb = 0; nb < 2; ++nb) {
            unsigned short pk[4];
#pragma unroll
            for (int r = 0; r < 4; ++r) pk[r] = f2b(p[nb][r]);
            *(uint2*)&Pt[w][l15][nb * 16 + quad * 4] = *(const uint2*)pk;
        }

        if (__any(need)) {                   // fetch per-q alpha, rescale o
#pragma unroll
            for (int r = 0; r < 4; ++r) {
                float al = __shfl(alpha, quad * 4 + r, 16);
#pragma unroll
                for (int nb2 = 0; nb2 < 8; ++nb2) o[nb2][r] *= al;
            }
        }

        asm volatile("s_waitcnt lgkmcnt(0)" ::: "memory");   // wave-local RAW on Pt[w]
        bfrag pf = *(const bfrag*)&Pt[w][l15][quad * 8];
#pragma unroll
        for (int nb2 = 0; nb2 < 8; ++nb2) {
            bfrag vf = *(const bfrag*)&Vt[cur][nb2 * 16 + l15][quad * 8];
            o[nb2] = __builtin_amdgcn_mfma_f32_16x16x32_bf16(pf, vf, o[nb2], 0, 0, 0);
        }
    }

    // final: fetch per-q l via width-16 shfl, divide, store
    float lr[4];
#pragma unroll
    for (int r = 0; r < 4; ++r) lr[r] = __shfl(lreg, quad * 4 + r, 16);
#pragma unroll
    for (int nb2 = 0; nb2 < 8; ++nb2)
#pragma unroll
        for (int r = 0; r < 4; ++r) {
            int qg = qbase + w * 16 + quad * 4 + r;
            att[(size_t)(b * TT + qg) * 2048 + h * 128 + nb2 * 16 + l15] =
                f2b(o[nb2][r] / lr[r]);
        }
}

__global__ __launch_bounds__(512, 4) void k_flash(const unsigned short* __restrict__ QKV,
                                                  const unsigned short* __restrict__ VbT,
                                                  unsigned short* __restrict__ att) {
    __shared__ alignas(16) unsigned short Ks[2][32][136];
    __shared__ alignas(16) unsigned short Vt[2][128][40];
    __shared__ alignas(16) unsigned short Pt[8][16][40];
    int bh = blockIdx.y;
    int b = bh >> 4, h = bh & 15;
    int kvh = h >> 2;
    int i = blockIdx.x;

    flash_pass(i * 128, b, h, kvh, QKV, VbT, att, Ks, Vt, Pt);
    __syncthreads();
    flash_pass((15 - i) * 128, b, h, kvh, QKV, VbT, att, Ks, Vt, Pt);
}

// ---------------------------------------------------------------------------
extern "C" void kernel_launch(void* const* d_in, const int* in_sizes, int n_in,
                              void* d_out, int out_size, void* d_ws, size_t ws_size,
                              hipStream_t stream) {
    const float* x  = (const float*)d_in[0];
    const float* Wq = (const float*)d_in[1];
    const float* Wk = (const float*)d_in[2];
    const float* Wv = (const float*)d_in[3];
    const float* Wo = (const float*)d_in[4];
    const int* pos  = (const int*)d_in[5];

    char* ws = (char*)d_ws;
    unsigned short* xb   = (unsigned short*)(ws + 0);          // 32 MB (8192x2048); reused as att out
    unsigned short* QKV  = (unsigned short*)(ws + 33554432);   // 48 MB (8192x3072)
    unsigned short* VbT  = (unsigned short*)(ws + 83886080);   //  8 MB (512x8192)
    unsigned short* WqT  = (unsigned short*)(ws + 92274688);   //  8 MB (2048x2048)
    unsigned short* WkvT = (unsigned short*)(ws + 100663296);  //  4 MB (1024x2048) -- contiguous with WqT
    unsigned short* WoT  = (unsigned short*)(ws + 104857600);  //  8 MB
    float2*         tab  = (float2*)(ws + 113246208);          //  1 MB rope trig table -> 114.25 MB

    // x convert + trig table (one launch)
    k_cvt_trig<<<8704, 256, 0, stream>>>(x, xb, tab, pos);

    // all four weight transposes (one launch)
    k_wt_all<<<2560, 256, 0, stream>>>(Wq, Wk, Wv, Wo, WqT, WkvT, WoT);

    // fused Q|K|V projection: 2-phase BK=64 (control arm)
    k_gemm2ph<64><<<dim3(24, 64), 256, 0, stream>>>(xb, WqT, QKV, 8192, 3072, 2048, 0);

    // rope-Q + rope-K + V-transpose (one launch; disjoint QKV columns)
    k_postq<<<21504, 256, 0, stream>>>(QKV, VbT, tab);

    // causal GQA flash attention (swapped-QK softmax) -> xb
    k_flash<<<dim3(8, 64), 512, 0, stream>>>(QKV, VbT, xb);

    // output projection -> fp32 d_out: 2-phase BK=32 (co-residency experiment)
    k_gemm2ph<32><<<dim3(16, 64), 256, 0, stream>>>(xb, WoT, d_out, 8192, 2048, 2048, 1);
}

// Round 12
// 565.354 us; speedup vs baseline: 1.0669x; 1.0669x over previous
//
#include <hip/hip_runtime.h>
#include <math.h>

#define TT 2048

typedef __attribute__((ext_vector_type(8))) short bfrag;   // 8 bf16 in 4 VGPRs
typedef __attribute__((ext_vector_type(4))) float facc;    // 4 fp32 acc

#define NEG_BIG (-1.0e30f)

typedef __attribute__((address_space(1))) const void gas_void;
typedef __attribute__((address_space(3))) void las_void;

__device__ __forceinline__ void gl_lds16(const void* g, void* l) {
    __builtin_amdgcn_global_load_lds((gas_void*)g, (las_void*)l, 16, 0, 0);
}

__device__ __forceinline__ unsigned short f2b(float f) {
    union { float f; unsigned int i; } v; v.f = f;
    unsigned int b = v.i;
    return (unsigned short)((b + 0x7FFFu + ((b >> 16) & 1u)) >> 16);  // RNE
}
__device__ __forceinline__ float b2f(unsigned short s) {
    union { unsigned int i; float f; } u; u.i = ((unsigned int)s) << 16; return u.f;
}
__device__ __forceinline__ void cvt8_f32(const float* __restrict__ p, unsigned short* d) {
    float4 lo = *(const float4*)p, hi = *(const float4*)(p + 4);
    d[0] = f2b(lo.x); d[1] = f2b(lo.y); d[2] = f2b(lo.z); d[3] = f2b(lo.w);
    d[4] = f2b(hi.x); d[5] = f2b(hi.y); d[6] = f2b(hi.z); d[7] = f2b(hi.w);
}

// ---------------------------------------------------------------------------
// Merged: fp32->bf16 convert of x (blocks 0..8191) + RoPE trig table
// (blocks 8192..8703). Per-thread code identical to the measured k_cvt/k_trig.
// ---------------------------------------------------------------------------
__global__ __launch_bounds__(256) void k_cvt_trig(const float* __restrict__ in,
                                                  unsigned short* __restrict__ out,
                                                  float2* __restrict__ tab,
                                                  const int* __restrict__ posPtr) {
    int bi = blockIdx.x;
    if (bi < 8192) {
        int c = bi * 256 + threadIdx.x;          // n8 = 2097152 exact
        unsigned short t[8];
        cvt8_f32(in + (size_t)c * 8, t);
        *(uint4*)(out + (size_t)c * 8) = *(const uint4*)t;
    } else {
        int tid = (bi - 8192) * 256 + threadIdx.x;   // 131072 total
        int i1 = tid & 63, t = tid >> 6;
        float p = (float)(*posPtr + t);
        float f = exp2f(-(float)i1 * 0.20762050595278f);
        float th = p * f;
        tab[tid] = make_float2(cosf(th), sinf(th));
    }
}

// ---------------------------------------------------------------------------
// Merged weight transpose+convert: all four W (2048 x N fp32) -> WT
// (N x 2048 bf16) in one launch. Flat decode:
//   [0,1024):    Wq -> WqT   (N=2048, bx=i&31, by=i>>5)
//   [1024,1280): Wk -> WkvT  (N=512,  bx=j&7,  by=j>>3)
//   [1280,1536): Wv -> WkvT+512*2048
//   [1536,2560): Wo -> WoT
// Inner code identical to the measured k_wt.
// ---------------------------------------------------------------------------
__global__ __launch_bounds__(256) void k_wt_all(const float* __restrict__ Wq,
                                                const float* __restrict__ Wk,
                                                const float* __restrict__ Wv,
                                                const float* __restrict__ Wo,
                                                unsigned short* __restrict__ WqT,
                                                unsigned short* __restrict__ WkvT,
                                                unsigned short* __restrict__ WoT) {
    __shared__ alignas(16) unsigned short tile[64][72];
    int i = blockIdx.x;
    const float* W; unsigned short* WT; int N, bx, by;
    if (i < 1024)      { W = Wq; WT = WqT; N = 2048; bx = i & 31; by = i >> 5; }
    else if (i < 1280) { int j = i - 1024; W = Wk; WT = WkvT; N = 512; bx = j & 7; by = j >> 3; }
    else if (i < 1536) { int j = i - 1280; W = Wv; WT = WkvT + (size_t)512 * 2048; N = 512; bx = j & 7; by = j >> 3; }
    else               { int j = i - 1536; W = Wo; WT = WoT; N = 2048; bx = j & 31; by = j >> 5; }
    int r0 = by * 64, c0 = bx * 64;
    int tid = threadIdx.x;
    for (int k = 0; k < 2; ++k) {
        int c = tid + k * 256;
        int row = c >> 3, c8 = (c & 7) * 8;
        unsigned short t[8];
        cvt8_f32(W + (size_t)(r0 + row) * N + c0 + c8, t);
        *(uint4*)&tile[row][c8] = *(const uint4*)t;
    }
    __syncthreads();
    for (int k = 0; k < 2; ++k) {
        int c = tid + k * 256;
        int col = c >> 3, r8 = (c & 7) * 8;
        unsigned short t[8];
        for (int j = 0; j < 8; ++j) t[j] = tile[r8 + j][col];
        *(uint4*)(WT + (size_t)(c0 + col) * 2048 + r0 + r8) = *(const uint4*)t;
    }
}

// ---------------------------------------------------------------------------
// Merged post-QKV pass: rope-Q (blocks [0,16384)), rope-K ([16384,20480)),
// V-transpose ([20480,21504)). rope writes cols <2560 of QKV; vt reads cols
// >=2560 -> disjoint, same-launch-safe. Inner code identical to measured
// k_rope / k_vt.
// ---------------------------------------------------------------------------
__global__ __launch_bounds__(256) void k_postq(unsigned short* __restrict__ QKV,
                                               unsigned short* __restrict__ VbT,
                                               const float2* __restrict__ tab) {
    __shared__ alignas(16) unsigned short tile[64][72];
    int bi = blockIdx.x;
    if (bi < 20480) {
        // rope: Q part (lognh=4, base QKV) or K part (lognh=2, base QKV+2048)
        unsigned short* X; int lognh, tid;
        if (bi < 16384) { X = QKV;        lognh = 4; tid = bi * 256 + threadIdx.x; }
        else            { X = QKV + 2048; lognh = 2; tid = (bi - 16384) * 256 + threadIdx.x; }
        int d2 = tid & 31;
        int nh = 1 << lognh;
        int h = (tid >> 5) & (nh - 1);
        int row = tid >> (5 + lognh);
        int t = row & (TT - 1);
        size_t base = (size_t)row * 3072 + h * 128 + d2 * 2;
        unsigned int ua = *(const unsigned int*)(X + base);
        unsigned int ub = *(const unsigned int*)(X + base + 64);
        float x1a = b2f((unsigned short)(ua & 0xffff));
        float x1b = b2f((unsigned short)(ua >> 16));
        float x2a = b2f((unsigned short)(ub & 0xffff));
        float x2b = b2f((unsigned short)(ub >> 16));
        float2 cs1 = tab[t * 64 + d2];
        float2 cs2 = tab[t * 64 + d2 + 32];
        unsigned int o1 = (unsigned int)f2b(x1a * cs1.x - x2a * cs1.y)
                        | ((unsigned int)f2b(x1b * cs1.x - x2b * cs1.y) << 16);
        unsigned int o2 = (unsigned int)f2b(x2a * cs2.x + x1a * cs2.y)
                        | ((unsigned int)f2b(x2b * cs2.x + x1b * cs2.y) << 16);
        *(unsigned int*)(X + base)      = o1;
        *(unsigned int*)(X + base + 64) = o2;
    } else {
        // V transpose: QKV cols 2560..3071 -> VbT (512 x 8192)
        int j = bi - 20480;
        int r0 = (j >> 3) * 64, c0 = (j & 7) * 64;
        int tid = threadIdx.x;
        for (int k = 0; k < 2; ++k) {
            int c = tid + k * 256;
            int row = c >> 3, c8 = (c & 7) * 8;
            *(uint4*)&tile[row][c8] =
                *(const uint4*)(QKV + (size_t)(r0 + row) * 3072 + 2560 + c0 + c8);
        }
        __syncthreads();
        for (int k = 0; k < 2; ++k) {
            int c = tid + k * 256;
            int col = c >> 3, r8 = (c & 7) * 8;
            unsigned short t[8];
            for (int jj = 0; jj < 8; ++jj) t[jj] = tile[r8 + jj][col];
            *(uint4*)(VbT + (size_t)(c0 + col) * 8192 + r0 + r8) = *(const uint4*)t;
        }
    }
}

// ---------------------------------------------------------------------------
// 2-phase double-buffered m97 GEMM, BK=64 LOCKED (round-11 A/B: BK=32's
// extra barriers/drains cost ~+40 us on O-proj despite 2x co-residency).
// Linear block mapping + locked XOR chunk swizzle (rounds 8/9 A/Bs).
// ---------------------------------------------------------------------------
__global__ __launch_bounds__(256) void k_gemm2ph(const unsigned short* __restrict__ A,
                                                 const unsigned short* __restrict__ Bt,
                                                 void* __restrict__ Cmat,
                                                 int M, int N, int K, int outF) {
    __shared__ union SM {
        struct { unsigned short A[2][128][64]; unsigned short B[2][128][64]; } s;  // 64 KB
        unsigned short ct[32][136];
        float          ctf[32][136];
    } sm;
    int tid = threadIdx.x;
    int w = tid >> 6, lane = tid & 63, quad = lane >> 4, l15 = lane & 15;
    int m0 = blockIdx.y * 128, n0 = blockIdx.x * 128;
    int wm = (w >> 1) * 64, wn = (w & 1) * 64;

    int srow   = lane >> 3;                 // 0..7
    int schunk = (lane & 7) ^ (lane >> 3);  // inverse-swizzled source chunk

    facc acc[4][4];
#pragma unroll
    for (int mi = 0; mi < 4; ++mi)
#pragma unroll
        for (int ni = 0; ni < 4; ++ni)
#pragma unroll
            for (int r = 0; r < 4; ++r) acc[mi][ni][r] = 0.f;

    auto stage = [&](int bb, int k0) {
#pragma unroll
        for (int i = 0; i < 4; ++i) {
            int row = w * 32 + i * 8;
            gl_lds16(A  + (size_t)(m0 + row + srow) * K + k0 + schunk * 8, &sm.s.A[bb][row][0]);
            gl_lds16(Bt + (size_t)(n0 + row + srow) * K + k0 + schunk * 8, &sm.s.B[bb][row][0]);
        }
    };

    int NT = K >> 6;
    stage(0, 0);
    __syncthreads();                        // implicit vmcnt(0): buf0 ready

    for (int t = 0; t < NT; ++t) {
        int cur = t & 1;
        if (t + 1 < NT) stage(cur ^ 1, (t + 1) * 64);   // hide under compute

        bfrag af[4][2], bf[4][2];
#pragma unroll
        for (int mi = 0; mi < 4; ++mi)
#pragma unroll
            for (int kc = 0; kc < 2; ++kc)
                af[mi][kc] = *(const bfrag*)&sm.s.A[cur][wm + mi * 16 + l15][((kc * 4 + quad) ^ (l15 & 7)) * 8];
#pragma unroll
        for (int ni = 0; ni < 4; ++ni)
#pragma unroll
            for (int kc = 0; kc < 2; ++kc)
                bf[ni][kc] = *(const bfrag*)&sm.s.B[cur][wn + ni * 16 + l15][((kc * 4 + quad) ^ (l15 & 7)) * 8];
#pragma unroll
        for (int kc = 0; kc < 2; ++kc)
#pragma unroll
            for (int mi = 0; mi < 4; ++mi)
#pragma unroll
                for (int ni = 0; ni < 4; ++ni)
                    acc[mi][ni] = __builtin_amdgcn_mfma_f32_16x16x32_bf16(af[mi][kc], bf[ni][kc], acc[mi][ni], 0, 0, 0);

        __syncthreads();                    // drains vmcnt (t+1 staged) + fences buf[cur]
    }

    // epilogue: 4 rounds; round t stages every wave's mi=t subtile (32x128)
#pragma unroll
    for (int t = 0; t < 4; ++t) {
        __syncthreads();
#pragma unroll
        for (int ni = 0; ni < 4; ++ni)
#pragma unroll
            for (int r = 0; r < 4; ++r) {
                int lr = (w >> 1) * 16 + quad * 4 + r;
                int lc = wn + ni * 16 + l15;
                if (outF) sm.ctf[lr][lc] = acc[t][ni][r];
                else      sm.ct [lr][lc] = f2b(acc[t][ni][r]);
            }
        __syncthreads();
        if (outF) {
#pragma unroll
            for (int i = 0; i < 4; ++i) {
                int cc = tid + i * 256;
                int lr = cc >> 5, c4 = (cc & 31) * 4;
                int grow = m0 + (lr >> 4) * 64 + t * 16 + (lr & 15);
                *(float4*)((float*)Cmat + (size_t)grow * N + n0 + c4) =
                    *(const float4*)&sm.ctf[lr][c4];
            }
        } else {
#pragma unroll
            for (int i = 0; i < 2; ++i) {
                int cc = tid + i * 256;
                int lr = cc >> 4, c8 = (cc & 15) * 8;
                int grow = m0 + (lr >> 4) * 64 + t * 16 + (lr & 15);
                *(uint4*)((unsigned short*)Cmat + (size_t)grow * N + n0 + c8) =
                    *(const uint4*)&sm.ct[lr][c8];
            }
        }
    }
}

// ---------------------------------------------------------------------------
// Flash attention, causal, GQA (round-7/10 measured-good config, unchanged):
// 512 threads, QBLK=128, paired q-tiles (i, 15-i); double-buffered K/V LDS,
// one barrier per K-step, register prefetch post-barrier; inactive-tile
// skip; interior fast path; T13 defer-max THR=8; swapped QK^T softmax.
// ---------------------------------------------------------------------------
__device__ __forceinline__ void flash_pass(
    int qbase, int b, int h, int kvh,
    const unsigned short* __restrict__ QKV,
    const unsigned short* __restrict__ VbT,
    unsigned short* __restrict__ att,
    unsigned short (&Ks)[2][32][136],
    unsigned short (&Vt)[2][128][40],
    unsigned short (&Pt)[8][16][40]) {

    int tid = threadIdx.x;
    int w = tid >> 6, lane = tid & 63, quad = lane >> 4, l15 = lane & 15;

    bfrag qf[4];
    {
        size_t qrow = (size_t)(b * TT + qbase + w * 16 + l15);
        for (int kc = 0; kc < 4; ++kc)
            qf[kc] = *(const bfrag*)(QKV + qrow * 3072 + h * 128 + kc * 32 + quad * 8);
    }

    float mreg = NEG_BIG, lreg = 0.f;      // state for q = qgmin + l15
    facc o[8];
#pragma unroll
    for (int nb2 = 0; nb2 < 8; ++nb2)
#pragma unroll
        for (int r = 0; r < 4; ++r) o[nb2][r] = 0.f;

    int krow = tid >> 4, d8 = (tid & 15) * 8;
    int vd = tid >> 2, tc = (tid & 3) * 8;
    const unsigned short* Kg = QKV + (size_t)(b * TT) * 3072 + 2048 + kvh * 128;
    const unsigned short* Vg = VbT + (size_t)(kvh * 128 + vd) * 8192 + b * TT;

    const float sc = 0.08838834764831845f;   // 1/sqrt(128)
    int kmax = qbase + 128;
    int nt = kmax >> 5;
    int qgmin = qbase + w * 16;
    int myq = qgmin + l15;                   // this lane's q-row

    uint4 rk = *(const uint4*)(Kg + (size_t)krow * 3072 + d8);
    uint4 rv = *(const uint4*)(Vg + tc);

    for (int t = 0; t < nt; ++t) {
        int cur = t & 1;
        int k0 = t * 32;
        *(uint4*)&Ks[cur][krow][d8] = rk;
        *(uint4*)&Vt[cur][vd][tc]   = rv;
        __syncthreads();

        if (t + 1 < nt) {
            int k0n = k0 + 32;
            rk = *(const uint4*)(Kg + (size_t)(k0n + krow) * 3072 + d8);
            rv = *(const uint4*)(Vg + k0n + tc);
        }

        if (k0 > qgmin + 15) continue;       // fully-masked tile for this wave

        // swapped QK^T: A = K-frag, B = Q-frag -> D[k][q], q = l15
        facc s[2];
#pragma unroll
        for (int nb = 0; nb < 2; ++nb) {
#pragma unroll
            for (int r = 0; r < 4; ++r) s[nb][r] = 0.f;
#pragma unroll
            for (int kc = 0; kc < 4; ++kc) {
                bfrag kf = *(const bfrag*)&Ks[cur][nb * 16 + l15][kc * 32 + quad * 8];
                s[nb] = __builtin_amdgcn_mfma_f32_16x16x32_bf16(kf, qf[kc], s[nb], 0, 0, 0);
            }
        }

        bool fullT = (k0 + 31) <= qgmin;
        float v[2][4];
        if (fullT) {
#pragma unroll
            for (int nb = 0; nb < 2; ++nb)
#pragma unroll
                for (int r = 0; r < 4; ++r) v[nb][r] = s[nb][r] * sc;
        } else {
#pragma unroll
            for (int nb = 0; nb < 2; ++nb)
#pragma unroll
                for (int r = 0; r < 4; ++r) {
                    int kg = k0 + nb * 16 + quad * 4 + r;
                    v[nb][r] = (kg > myq) ? NEG_BIG : s[nb][r] * sc;
                }
        }

        // row max: 7 local fmax + 2-step fold
        float mx = fmaxf(fmaxf(fmaxf(v[0][0], v[0][1]), fmaxf(v[0][2], v[0][3])),
                         fmaxf(fmaxf(v[1][0], v[1][1]), fmaxf(v[1][2], v[1][3])));
        mx = fmaxf(mx, __shfl_xor(mx, 16, 64));
        mx = fmaxf(mx, __shfl_xor(mx, 32, 64));

        bool need = (mx > mreg + 8.f);       // T13 defer-max, THR=8
        float mnew = need ? mx : mreg;
        float alpha = need ? __expf(mreg - mnew) : 1.f;

        float p[2][4];
        float psum = 0.f;
#pragma unroll
        for (int nb = 0; nb < 2; ++nb)
#pragma unroll
            for (int r = 0; r < 4; ++r) {
                p[nb][r] = __expf(v[nb][r] - mnew);   // exp(-huge)=0 for masked
                psum += p[nb][r];
            }
        psum += __shfl_xor(psum, 16, 64);
        psum += __shfl_xor(psum, 32, 64);
        lreg = lreg * alpha + psum;
        mreg = mnew;

        // P -> LDS: lane writes 4 contiguous k per nb (8B each)
#pragma unroll
        for (int nb = 0; nb < 2; ++nb) {
            unsigned short pk[4];
#pragma unroll
            for (int r = 0; r < 4; ++r) pk[r] = f2b(p[nb][r]);
            *(uint2*)&Pt[w][l15][nb * 16 + quad * 4] = *(const uint2*)pk;
        }

        if (__any(need)) {                   // fetch per-q alpha, rescale o
#pragma unroll
            for (int r = 0; r < 4; ++r) {
                float al = __shfl(alpha, quad * 4 + r, 16);
#pragma unroll
                for (int nb2 = 0; nb2 < 8; ++nb2) o[nb2][r] *= al;
            }
        }

        asm volatile("s_waitcnt lgkmcnt(0)" ::: "memory");   // wave-local RAW on Pt[w]
        bfrag pf = *(const bfrag*)&Pt[w][l15][quad * 8];
#pragma unroll
        for (int nb2 = 0; nb2 < 8; ++nb2) {
            bfrag vf = *(const bfrag*)&Vt[cur][nb2 * 16 + l15][quad * 8];
            o[nb2] = __builtin_amdgcn_mfma_f32_16x16x32_bf16(pf, vf, o[nb2], 0, 0, 0);
        }
    }

    // final: fetch per-q l via width-16 shfl, divide, store
    float lr[4];
#pragma unroll
    for (int r = 0; r < 4; ++r) lr[r] = __shfl(lreg, quad * 4 + r, 16);
#pragma unroll
    for (int nb2 = 0; nb2 < 8; ++nb2)
#pragma unroll
        for (int r = 0; r < 4; ++r) {
            int qg = qbase + w * 16 + quad * 4 + r;
            att[(size_t)(b * TT + qg) * 2048 + h * 128 + nb2 * 16 + l15] =
                f2b(o[nb2][r] / lr[r]);
        }
}

__global__ __launch_bounds__(512, 4) void k_flash(const unsigned short* __restrict__ QKV,
                                                  const unsigned short* __restrict__ VbT,
                                                  unsigned short* __restrict__ att) {
    __shared__ alignas(16) unsigned short Ks[2][32][136];
    __shared__ alignas(16) unsigned short Vt[2][128][40];
    __shared__ alignas(16) unsigned short Pt[8][16][40];
    int bh = blockIdx.y;
    int b = bh >> 4, h = bh & 15;
    int kvh = h >> 2;
    int i = blockIdx.x;

    flash_pass(i * 128, b, h, kvh, QKV, VbT, att, Ks, Vt, Pt);
    __syncthreads();
    flash_pass((15 - i) * 128, b, h, kvh, QKV, VbT, att, Ks, Vt, Pt);
}

// ---------------------------------------------------------------------------
extern "C" void kernel_launch(void* const* d_in, const int* in_sizes, int n_in,
                              void* d_out, int out_size, void* d_ws, size_t ws_size,
                              hipStream_t stream) {
    const float* x  = (const float*)d_in[0];
    const float* Wq = (const float*)d_in[1];
    const float* Wk = (const float*)d_in[2];
    const float* Wv = (const float*)d_in[3];
    const float* Wo = (const float*)d_in[4];
    const int* pos  = (const int*)d_in[5];

    char* ws = (char*)d_ws;
    unsigned short* xb   = (unsigned short*)(ws + 0);          // 32 MB (8192x2048); reused as att out
    unsigned short* QKV  = (unsigned short*)(ws + 33554432);   // 48 MB (8192x3072)
    unsigned short* VbT  = (unsigned short*)(ws + 83886080);   //  8 MB (512x8192)
    unsigned short* WqT  = (unsigned short*)(ws + 92274688);   //  8 MB (2048x2048)
    unsigned short* WkvT = (unsigned short*)(ws + 100663296);  //  4 MB (1024x2048) -- contiguous with WqT
    unsigned short* WoT  = (unsigned short*)(ws + 104857600);  //  8 MB
    float2*         tab  = (float2*)(ws + 113246208);          //  1 MB rope trig table -> 114.25 MB

    // x convert + trig table (one launch)
    k_cvt_trig<<<8704, 256, 0, stream>>>(x, xb, tab, pos);

    // all four weight transposes (one launch)
    k_wt_all<<<2560, 256, 0, stream>>>(Wq, Wk, Wv, Wo, WqT, WkvT, WoT);

    // fused Q|K|V projection: 2-phase BK=64 (locked)
    k_gemm2ph<<<dim3(24, 64), 256, 0, stream>>>(xb, WqT, QKV, 8192, 3072, 2048, 0);

    // rope-Q + rope-K + V-transpose (one launch; disjoint QKV columns)
    k_postq<<<21504, 256, 0, stream>>>(QKV, VbT, tab);

    // causal GQA flash attention (swapped-QK softmax) -> xb
    k_flash<<<dim3(8, 64), 512, 0, stream>>>(QKV, VbT, xb);

    // output projection -> fp32 d_out: 2-phase BK=64 (locked)
    k_gemm2ph<<<dim3(16, 64), 256, 0, stream>>>(xb, WoT, d_out, 8192, 2048, 2048, 1);
}

// Round 13
// 557.501 us; speedup vs baseline: 1.0819x; 1.0141x over previous
//
#include <hip/hip_runtime.h>
#include <math.h>

#define TT 2048

typedef __attribute__((ext_vector_type(8))) short bfrag;   // 8 bf16 in 4 VGPRs
typedef __attribute__((ext_vector_type(4))) float facc;    // 4 fp32 acc

#define NEG_BIG (-1.0e30f)

typedef __attribute__((address_space(1))) const void gas_void;
typedef __attribute__((address_space(3))) void las_void;

__device__ __forceinline__ void gl_lds16(const void* g, void* l) {
    __builtin_amdgcn_global_load_lds((gas_void*)g, (las_void*)l, 16, 0, 0);
}

__device__ __forceinline__ unsigned short f2b(float f) {
    union { float f; unsigned int i; } v; v.f = f;
    unsigned int b = v.i;
    return (unsigned short)((b + 0x7FFFu + ((b >> 16) & 1u)) >> 16);  // RNE
}
__device__ __forceinline__ float b2f(unsigned short s) {
    union { unsigned int i; float f; } u; u.i = ((unsigned int)s) << 16; return u.f;
}
__device__ __forceinline__ void cvt8_f32(const float* __restrict__ p, unsigned short* d) {
    float4 lo = *(const float4*)p, hi = *(const float4*)(p + 4);
    d[0] = f2b(lo.x); d[1] = f2b(lo.y); d[2] = f2b(lo.z); d[3] = f2b(lo.w);
    d[4] = f2b(hi.x); d[5] = f2b(hi.y); d[6] = f2b(hi.z); d[7] = f2b(hi.w);
}

// ---------------------------------------------------------------------------
// Merged preprocessing (one launch):
//   [0,8192):     fp32->bf16 convert of x      (identical to measured k_cvt)
//   [8192,8704):  RoPE trig table              (identical to measured k_trig)
//   [8704,11264): all four weight transposes   (identical to measured k_wt_all)
// ---------------------------------------------------------------------------
__global__ __launch_bounds__(256) void k_pre(const float* __restrict__ x,
                                             unsigned short* __restrict__ xb,
                                             float2* __restrict__ tab,
                                             const int* __restrict__ posPtr,
                                             const float* __restrict__ Wq,
                                             const float* __restrict__ Wk,
                                             const float* __restrict__ Wv,
                                             const float* __restrict__ Wo,
                                             unsigned short* __restrict__ WqT,
                                             unsigned short* __restrict__ WkvT,
                                             unsigned short* __restrict__ WoT) {
    __shared__ alignas(16) unsigned short tile[64][72];
    int bi = blockIdx.x;
    if (bi < 8192) {
        int c = bi * 256 + threadIdx.x;          // n8 = 2097152 exact
        unsigned short t[8];
        cvt8_f32(x + (size_t)c * 8, t);
        *(uint4*)(xb + (size_t)c * 8) = *(const uint4*)t;
    } else if (bi < 8704) {
        int tid = (bi - 8192) * 256 + threadIdx.x;   // 131072 total
        int i1 = tid & 63, t = tid >> 6;
        float p = (float)(*posPtr + t);
        float f = exp2f(-(float)i1 * 0.20762050595278f);
        float th = p * f;
        tab[tid] = make_float2(cosf(th), sinf(th));
    } else {
        int i = bi - 8704;
        const float* W; unsigned short* WT; int N, bx, by;
        if (i < 1024)      { W = Wq; WT = WqT; N = 2048; bx = i & 31; by = i >> 5; }
        else if (i < 1280) { int j = i - 1024; W = Wk; WT = WkvT; N = 512; bx = j & 7; by = j >> 3; }
        else if (i < 1536) { int j = i - 1280; W = Wv; WT = WkvT + (size_t)512 * 2048; N = 512; bx = j & 7; by = j >> 3; }
        else               { int j = i - 1536; W = Wo; WT = WoT; N = 2048; bx = j & 31; by = j >> 5; }
        int r0 = by * 64, c0 = bx * 64;
        int tid = threadIdx.x;
        for (int k = 0; k < 2; ++k) {
            int c = tid + k * 256;
            int row = c >> 3, c8 = (c & 7) * 8;
            unsigned short t[8];
            cvt8_f32(W + (size_t)(r0 + row) * N + c0 + c8, t);
            *(uint4*)&tile[row][c8] = *(const uint4*)t;
        }
        __syncthreads();
        for (int k = 0; k < 2; ++k) {
            int c = tid + k * 256;
            int col = c >> 3, r8 = (c & 7) * 8;
            unsigned short t[8];
            for (int j = 0; j < 8; ++j) t[j] = tile[r8 + j][col];
            *(uint4*)(WT + (size_t)(c0 + col) * 2048 + r0 + r8) = *(const uint4*)t;
        }
    }
}

// ---------------------------------------------------------------------------
// V transpose: QKV (8192 x 3072 bf16, V = cols 2560..3071) -> VbT (512 x 8192)
// (rope for Q/K now lives in the QKV GEMM epilogue)
// ---------------------------------------------------------------------------
__global__ __launch_bounds__(256) void k_vt(const unsigned short* __restrict__ QKV,
                                            unsigned short* __restrict__ VbT) {
    __shared__ alignas(16) unsigned short tile[64][72];
    int j = blockIdx.x;
    int r0 = (j >> 3) * 64, c0 = (j & 7) * 64;
    int tid = threadIdx.x;
    for (int k = 0; k < 2; ++k) {
        int c = tid + k * 256;
        int row = c >> 3, c8 = (c & 7) * 8;
        *(uint4*)&tile[row][c8] =
            *(const uint4*)(QKV + (size_t)(r0 + row) * 3072 + 2560 + c0 + c8);
    }
    __syncthreads();
    for (int k = 0; k < 2; ++k) {
        int c = tid + k * 256;
        int col = c >> 3, r8 = (c & 7) * 8;
        unsigned short t[8];
        for (int jj = 0; jj < 8; ++jj) t[jj] = tile[r8 + jj][col];
        *(uint4*)(VbT + (size_t)(c0 + col) * 8192 + r0 + r8) = *(const uint4*)t;
    }
}

// ---------------------------------------------------------------------------
// 2-phase double-buffered m97 GEMM, BK=64 / linear mapping / XOR swizzle all
// LOCKED (rounds 8/9/11 A/Bs). ROPE template (QKV only): table-driven rope
// applied in the bf16 epilogue to cols < 2560 -- round-3's verified fusion
// minus its two failure causes: no transcendentals (table loads + FMA only)
// and no runtime branch (template; col<2560 test is block-uniform since n0
// is a multiple of 128). Reads the bf16-rounded value + its c8^64 partner
// from the staged LDS tile -> bit-identical to the separate k_rope pass.
// Spill markers to watch: VGPR <= ~110, WRITE_SIZE == 49152 KB.
// ---------------------------------------------------------------------------
template <int ROPE>
__global__ __launch_bounds__(256) void k_gemm2ph(const unsigned short* __restrict__ A,
                                                 const unsigned short* __restrict__ Bt,
                                                 void* __restrict__ Cmat,
                                                 int M, int N, int K, int outF,
                                                 const float2* __restrict__ tab) {
    __shared__ union SM {
        struct { unsigned short A[2][128][64]; unsigned short B[2][128][64]; } s;  // 64 KB
        unsigned short ct[32][136];
        float          ctf[32][136];
    } sm;
    int tid = threadIdx.x;
    int w = tid >> 6, lane = tid & 63, quad = lane >> 4, l15 = lane & 15;
    int m0 = blockIdx.y * 128, n0 = blockIdx.x * 128;
    int wm = (w >> 1) * 64, wn = (w & 1) * 64;

    int srow   = lane >> 3;                 // 0..7
    int schunk = (lane & 7) ^ (lane >> 3);  // inverse-swizzled source chunk

    facc acc[4][4];
#pragma unroll
    for (int mi = 0; mi < 4; ++mi)
#pragma unroll
        for (int ni = 0; ni < 4; ++ni)
#pragma unroll
            for (int r = 0; r < 4; ++r) acc[mi][ni][r] = 0.f;

    auto stage = [&](int bb, int k0) {
#pragma unroll
        for (int i = 0; i < 4; ++i) {
            int row = w * 32 + i * 8;
            gl_lds16(A  + (size_t)(m0 + row + srow) * K + k0 + schunk * 8, &sm.s.A[bb][row][0]);
            gl_lds16(Bt + (size_t)(n0 + row + srow) * K + k0 + schunk * 8, &sm.s.B[bb][row][0]);
        }
    };

    int NT = K >> 6;
    stage(0, 0);
    __syncthreads();                        // implicit vmcnt(0): buf0 ready

    for (int t = 0; t < NT; ++t) {
        int cur = t & 1;
        if (t + 1 < NT) stage(cur ^ 1, (t + 1) * 64);   // hide under compute

        bfrag af[4][2], bf[4][2];
#pragma unroll
        for (int mi = 0; mi < 4; ++mi)
#pragma unroll
            for (int kc = 0; kc < 2; ++kc)
                af[mi][kc] = *(const bfrag*)&sm.s.A[cur][wm + mi * 16 + l15][((kc * 4 + quad) ^ (l15 & 7)) * 8];
#pragma unroll
        for (int ni = 0; ni < 4; ++ni)
#pragma unroll
            for (int kc = 0; kc < 2; ++kc)
                bf[ni][kc] = *(const bfrag*)&sm.s.B[cur][wn + ni * 16 + l15][((kc * 4 + quad) ^ (l15 & 7)) * 8];
#pragma unroll
        for (int kc = 0; kc < 2; ++kc)
#pragma unroll
            for (int mi = 0; mi < 4; ++mi)
#pragma unroll
                for (int ni = 0; ni < 4; ++ni)
                    acc[mi][ni] = __builtin_amdgcn_mfma_f32_16x16x32_bf16(af[mi][kc], bf[ni][kc], acc[mi][ni], 0, 0, 0);

        __syncthreads();                    // drains vmcnt (t+1 staged) + fences buf[cur]
    }

    // epilogue: 4 rounds; round t stages every wave's mi=t subtile (32x128)
#pragma unroll
    for (int t = 0; t < 4; ++t) {
        __syncthreads();
#pragma unroll
        for (int ni = 0; ni < 4; ++ni)
#pragma unroll
            for (int r = 0; r < 4; ++r) {
                int lr = (w >> 1) * 16 + quad * 4 + r;
                int lc = wn + ni * 16 + l15;
                if (outF) sm.ctf[lr][lc] = acc[t][ni][r];
                else      sm.ct [lr][lc] = f2b(acc[t][ni][r]);
            }
        __syncthreads();
        if (outF) {
#pragma unroll
            for (int i = 0; i < 4; ++i) {
                int cc = tid + i * 256;
                int lr = cc >> 5, c4 = (cc & 31) * 4;
                int grow = m0 + (lr >> 4) * 64 + t * 16 + (lr & 15);
                *(float4*)((float*)Cmat + (size_t)grow * N + n0 + c4) =
                    *(const float4*)&sm.ctf[lr][c4];
            }
        } else {
#pragma unroll
            for (int i = 0; i < 2; ++i) {
                int cc = tid + i * 256;
                int lr = cc >> 4, c8 = (cc & 15) * 8;
                int grow = m0 + (lr >> 4) * 64 + t * 16 + (lr & 15);
                uint4 val = *(const uint4*)&sm.ct[lr][c8];
                if constexpr (ROPE) {
                    if (n0 < 2560) {                  // block-uniform guard
                        unsigned short prt[8];
                        *(uint4*)prt = *(const uint4*)&sm.ct[lr][c8 ^ 64];
                        unsigned short* sp = (unsigned short*)&val;
                        int tt = grow & (TT - 1);
                        int d = (n0 + c8) & 127;      // heads are 128-aligned
                        int hi = d & 64;
                        const float2* tb = tab + tt * 64 + ((d & 63) >> 1) + (hi ? 32 : 0);
                        float2 cs0 = tb[0], cs1 = tb[1], cs2 = tb[2], cs3 = tb[3];
                        float2 cs[4] = {cs0, cs1, cs2, cs3};
#pragma unroll
                        for (int j = 0; j < 8; ++j) {
                            float a = b2f(sp[j]), bq = b2f(prt[j]);
                            float c = cs[j >> 1].x, s = cs[j >> 1].y;
                            sp[j] = f2b(hi ? (a * c + bq * s) : (a * c - bq * s));
                        }
                    }
                }
                *(uint4*)((unsigned short*)Cmat + (size_t)grow * N + n0 + c8) = val;
            }
        }
    }
}

// ---------------------------------------------------------------------------
// Flash attention, causal, GQA (round-7/10/12 measured-good config,
// unchanged): 512 threads, QBLK=128, paired q-tiles (i, 15-i);
// double-buffered K/V LDS, one barrier per K-step, register prefetch
// post-barrier; inactive-tile skip; interior fast path; T13 defer-max
// THR=8; swapped QK^T softmax.
// ---------------------------------------------------------------------------
__device__ __forceinline__ void flash_pass(
    int qbase, int b, int h, int kvh,
    const unsigned short* __restrict__ QKV,
    const unsigned short* __restrict__ VbT,
    unsigned short* __restrict__ att,
    unsigned short (&Ks)[2][32][136],
    unsigned short (&Vt)[2][128][40],
    unsigned short (&Pt)[8][16][40]) {

    int tid = threadIdx.x;
    int w = tid >> 6, lane = tid & 63, quad = lane >> 4, l15 = lane & 15;

    bfrag qf[4];
    {
        size_t qrow = (size_t)(b * TT + qbase + w * 16 + l15);
        for (int kc = 0; kc < 4; ++kc)
            qf[kc] = *(const bfrag*)(QKV + qrow * 3072 + h * 128 + kc * 32 + quad * 8);
    }

    float mreg = NEG_BIG, lreg = 0.f;      // state for q = qgmin + l15
    facc o[8];
#pragma unroll
    for (int nb2 = 0; nb2 < 8; ++nb2)
#pragma unroll
        for (int r = 0; r < 4; ++r) o[nb2][r] = 0.f;

    int krow = tid >> 4, d8 = (tid & 15) * 8;
    int vd = tid >> 2, tc = (tid & 3) * 8;
    const unsigned short* Kg = QKV + (size_t)(b * TT) * 3072 + 2048 + kvh * 128;
    const unsigned short* Vg = VbT + (size_t)(kvh * 128 + vd) * 8192 + b * TT;

    const float sc = 0.08838834764831845f;   // 1/sqrt(128)
    int kmax = qbase + 128;
    int nt = kmax >> 5;
    int qgmin = qbase + w * 16;
    int myq = qgmin + l15;                   // this lane's q-row

    uint4 rk = *(const uint4*)(Kg + (size_t)krow * 3072 + d8);
    uint4 rv = *(const uint4*)(Vg + tc);

    for (int t = 0; t < nt; ++t) {
        int cur = t & 1;
        int k0 = t * 32;
        *(uint4*)&Ks[cur][krow][d8] = rk;
        *(uint4*)&Vt[cur][vd][tc]   = rv;
        __syncthreads();

        if (t + 1 < nt) {
            int k0n = k0 + 32;
            rk = *(const uint4*)(Kg + (size_t)(k0n + krow) * 3072 + d8);
            rv = *(const uint4*)(Vg + k0n + tc);
        }

        if (k0 > qgmin + 15) continue;       // fully-masked tile for this wave

        // swapped QK^T: A = K-frag, B = Q-frag -> D[k][q], q = l15
        facc s[2];
#pragma unroll
        for (int nb = 0; nb < 2; ++nb) {
#pragma unroll
            for (int r = 0; r < 4; ++r) s[nb][r] = 0.f;
#pragma unroll
            for (int kc = 0; kc < 4; ++kc) {
                bfrag kf = *(const bfrag*)&Ks[cur][nb * 16 + l15][kc * 32 + quad * 8];
                s[nb] = __builtin_amdgcn_mfma_f32_16x16x32_bf16(kf, qf[kc], s[nb], 0, 0, 0);
            }
        }

        bool fullT = (k0 + 31) <= qgmin;
        float v[2][4];
        if (fullT) {
#pragma unroll
            for (int nb = 0; nb < 2; ++nb)
#pragma unroll
                for (int r = 0; r < 4; ++r) v[nb][r] = s[nb][r] * sc;
        } else {
#pragma unroll
            for (int nb = 0; nb < 2; ++nb)
#pragma unroll
                for (int r = 0; r < 4; ++r) {
                    int kg = k0 + nb * 16 + quad * 4 + r;
                    v[nb][r] = (kg > myq) ? NEG_BIG : s[nb][r] * sc;
                }
        }

        // row max: 7 local fmax + 2-step fold
        float mx = fmaxf(fmaxf(fmaxf(v[0][0], v[0][1]), fmaxf(v[0][2], v[0][3])),
                         fmaxf(fmaxf(v[1][0], v[1][1]), fmaxf(v[1][2], v[1][3])));
        mx = fmaxf(mx, __shfl_xor(mx, 16, 64));
        mx = fmaxf(mx, __shfl_xor(mx, 32, 64));

        bool need = (mx > mreg + 8.f);       // T13 defer-max, THR=8
        float mnew = need ? mx : mreg;
        float alpha = need ? __expf(mreg - mnew) : 1.f;

        float p[2][4];
        float psum = 0.f;
#pragma unroll
        for (int nb = 0; nb < 2; ++nb)
#pragma unroll
            for (int r = 0; r < 4; ++r) {
                p[nb][r] = __expf(v[nb][r] - mnew);   // exp(-huge)=0 for masked
                psum += p[nb][r];
            }
        psum += __shfl_xor(psum, 16, 64);
        psum += __shfl_xor(psum, 32, 64);
        lreg = lreg * alpha + psum;
        mreg = mnew;

        // P -> LDS: lane writes 4 contiguous k per nb (8B each)
#pragma unroll
        for (int nb = 0; nb < 2; ++nb) {
            unsigned short pk[4];
#pragma unroll
            for (int r = 0; r < 4; ++r) pk[r] = f2b(p[nb][r]);
            *(uint2*)&Pt[w][l15][nb * 16 + quad * 4] = *(const uint2*)pk;
        }

        if (__any(need)) {                   // fetch per-q alpha, rescale o
#pragma unroll
            for (int r = 0; r < 4; ++r) {
                float al = __shfl(alpha, quad * 4 + r, 16);
#pragma unroll
                for (int nb2 = 0; nb2 < 8; ++nb2) o[nb2][r] *= al;
            }
        }

        asm volatile("s_waitcnt lgkmcnt(0)" ::: "memory");   // wave-local RAW on Pt[w]
        bfrag pf = *(const bfrag*)&Pt[w][l15][quad * 8];
#pragma unroll
        for (int nb2 = 0; nb2 < 8; ++nb2) {
            bfrag vf = *(const bfrag*)&Vt[cur][nb2 * 16 + l15][quad * 8];
            o[nb2] = __builtin_amdgcn_mfma_f32_16x16x32_bf16(pf, vf, o[nb2], 0, 0, 0);
        }
    }

    // final: fetch per-q l via width-16 shfl, divide, store
    float lr[4];
#pragma unroll
    for (int r = 0; r < 4; ++r) lr[r] = __shfl(lreg, quad * 4 + r, 16);
#pragma unroll
    for (int nb2 = 0; nb2 < 8; ++nb2)
#pragma unroll
        for (int r = 0; r < 4; ++r) {
            int qg = qbase + w * 16 + quad * 4 + r;
            att[(size_t)(b * TT + qg) * 2048 + h * 128 + nb2 * 16 + l15] =
                f2b(o[nb2][r] / lr[r]);
        }
}

__global__ __launch_bounds__(512, 4) void k_flash(const unsigned short* __restrict__ QKV,
                                                  const unsigned short* __restrict__ VbT,
                                                  unsigned short* __restrict__ att) {
    __shared__ alignas(16) unsigned short Ks[2][32][136];
    __shared__ alignas(16) unsigned short Vt[2][128][40];
    __shared__ alignas(16) unsigned short Pt[8][16][40];
    int bh = blockIdx.y;
    int b = bh >> 4, h = bh & 15;
    int kvh = h >> 2;
    int i = blockIdx.x;

    flash_pass(i * 128, b, h, kvh, QKV, VbT, att, Ks, Vt, Pt);
    __syncthreads();
    flash_pass((15 - i) * 128, b, h, kvh, QKV, VbT, att, Ks, Vt, Pt);
}

// ---------------------------------------------------------------------------
extern "C" void kernel_launch(void* const* d_in, const int* in_sizes, int n_in,
                              void* d_out, int out_size, void* d_ws, size_t ws_size,
                              hipStream_t stream) {
    const float* x  = (const float*)d_in[0];
    const float* Wq = (const float*)d_in[1];
    const float* Wk = (const float*)d_in[2];
    const float* Wv = (const float*)d_in[3];
    const float* Wo = (const float*)d_in[4];
    const int* pos  = (const int*)d_in[5];

    char* ws = (char*)d_ws;
    unsigned short* xb   = (unsigned short*)(ws + 0);          // 32 MB (8192x2048); reused as att out
    unsigned short* QKV  = (unsigned short*)(ws + 33554432);   // 48 MB (8192x3072)
    unsigned short* VbT  = (unsigned short*)(ws + 83886080);   //  8 MB (512x8192)
    unsigned short* WqT  = (unsigned short*)(ws + 92274688);   //  8 MB (2048x2048)
    unsigned short* WkvT = (unsigned short*)(ws + 100663296);  //  4 MB (1024x2048) -- contiguous with WqT
    unsigned short* WoT  = (unsigned short*)(ws + 104857600);  //  8 MB
    float2*         tab  = (float2*)(ws + 113246208);          //  1 MB rope trig table -> 114.25 MB

    // x convert + trig table + all weight transposes (one launch)
    k_pre<<<11264, 256, 0, stream>>>(x, xb, tab, pos, Wq, Wk, Wv, Wo, WqT, WkvT, WoT);

    // fused Q|K|V projection with table-driven rope in the epilogue
    k_gemm2ph<1><<<dim3(24, 64), 256, 0, stream>>>(xb, WqT, QKV, 8192, 3072, 2048, 0, tab);

    // V transpose for flash B-frag staging
    k_vt<<<1024, 256, 0, stream>>>(QKV, VbT);

    // causal GQA flash attention (swapped-QK softmax) -> xb
    k_flash<<<dim3(8, 64), 512, 0, stream>>>(QKV, VbT, xb);

    // output projection -> fp32 d_out
    k_gemm2ph<0><<<dim3(16, 64), 256, 0, stream>>>(xb, WoT, d_out, 8192, 2048, 2048, 1, nullptr);
}

// Round 14
// 555.091 us; speedup vs baseline: 1.0866x; 1.0043x over previous
//
#include <hip/hip_runtime.h>
#include <math.h>

#define TT 2048

typedef __attribute__((ext_vector_type(8))) short bfrag;   // 8 bf16 in 4 VGPRs
typedef __attribute__((ext_vector_type(4))) float facc;    // 4 fp32 acc

#define NEG_BIG (-1.0e30f)

typedef __attribute__((address_space(1))) const void gas_void;
typedef __attribute__((address_space(3))) void las_void;

__device__ __forceinline__ void gl_lds16(const void* g, void* l) {
    __builtin_amdgcn_global_load_lds((gas_void*)g, (las_void*)l, 16, 0, 0);
}

__device__ __forceinline__ unsigned short f2b(float f) {
    union { float f; unsigned int i; } v; v.f = f;
    unsigned int b = v.i;
    return (unsigned short)((b + 0x7FFFu + ((b >> 16) & 1u)) >> 16);  // RNE
}
__device__ __forceinline__ float b2f(unsigned short s) {
    union { unsigned int i; float f; } u; u.i = ((unsigned int)s) << 16; return u.f;
}
// HW packed fp32->bf16 RNE (bit-identical to f2b for finite values; P/O paths
// are finite). T12 context: m214-v22 used this exact pattern at +9%.
__device__ __forceinline__ unsigned int cvtpk_bf16(float lo, float hi) {
    unsigned int r;
    asm("v_cvt_pk_bf16_f32 %0, %1, %2" : "=v"(r) : "v"(lo), "v"(hi));
    return r;
}
__device__ __forceinline__ void cvt8_f32(const float* __restrict__ p, unsigned short* d) {
    float4 lo = *(const float4*)p, hi = *(const float4*)(p + 4);
    d[0] = f2b(lo.x); d[1] = f2b(lo.y); d[2] = f2b(lo.z); d[3] = f2b(lo.w);
    d[4] = f2b(hi.x); d[5] = f2b(hi.y); d[6] = f2b(hi.z); d[7] = f2b(hi.w);
}

// ---------------------------------------------------------------------------
// Merged preprocessing (one launch):
//   [0,8192):     fp32->bf16 convert of x      (identical to measured k_cvt)
//   [8192,8704):  RoPE trig table              (identical to measured k_trig)
//   [8704,11264): all four weight transposes   (identical to measured k_wt_all)
// ---------------------------------------------------------------------------
__global__ __launch_bounds__(256) void k_pre(const float* __restrict__ x,
                                             unsigned short* __restrict__ xb,
                                             float2* __restrict__ tab,
                                             const int* __restrict__ posPtr,
                                             const float* __restrict__ Wq,
                                             const float* __restrict__ Wk,
                                             const float* __restrict__ Wv,
                                             const float* __restrict__ Wo,
                                             unsigned short* __restrict__ WqT,
                                             unsigned short* __restrict__ WkvT,
                                             unsigned short* __restrict__ WoT) {
    __shared__ alignas(16) unsigned short tile[64][72];
    int bi = blockIdx.x;
    if (bi < 8192) {
        int c = bi * 256 + threadIdx.x;          // n8 = 2097152 exact
        unsigned short t[8];
        cvt8_f32(x + (size_t)c * 8, t);
        *(uint4*)(xb + (size_t)c * 8) = *(const uint4*)t;
    } else if (bi < 8704) {
        int tid = (bi - 8192) * 256 + threadIdx.x;   // 131072 total
        int i1 = tid & 63, t = tid >> 6;
        float p = (float)(*posPtr + t);
        float f = exp2f(-(float)i1 * 0.20762050595278f);
        float th = p * f;
        tab[tid] = make_float2(cosf(th), sinf(th));
    } else {
        int i = bi - 8704;
        const float* W; unsigned short* WT; int N, bx, by;
        if (i < 1024)      { W = Wq; WT = WqT; N = 2048; bx = i & 31; by = i >> 5; }
        else if (i < 1280) { int j = i - 1024; W = Wk; WT = WkvT; N = 512; bx = j & 7; by = j >> 3; }
        else if (i < 1536) { int j = i - 1280; W = Wv; WT = WkvT + (size_t)512 * 2048; N = 512; bx = j & 7; by = j >> 3; }
        else               { int j = i - 1536; W = Wo; WT = WoT; N = 2048; bx = j & 31; by = j >> 5; }
        int r0 = by * 64, c0 = bx * 64;
        int tid = threadIdx.x;
        for (int k = 0; k < 2; ++k) {
            int c = tid + k * 256;
            int row = c >> 3, c8 = (c & 7) * 8;
            unsigned short t[8];
            cvt8_f32(W + (size_t)(r0 + row) * N + c0 + c8, t);
            *(uint4*)&tile[row][c8] = *(const uint4*)t;
        }
        __syncthreads();
        for (int k = 0; k < 2; ++k) {
            int c = tid + k * 256;
            int col = c >> 3, r8 = (c & 7) * 8;
            unsigned short t[8];
            for (int j = 0; j < 8; ++j) t[j] = tile[r8 + j][col];
            *(uint4*)(WT + (size_t)(c0 + col) * 2048 + r0 + r8) = *(const uint4*)t;
        }
    }
}

// ---------------------------------------------------------------------------
// V transpose: QKV (8192 x 3072 bf16, V = cols 2560..3071) -> VbT (512 x 8192)
// ---------------------------------------------------------------------------
__global__ __launch_bounds__(256) void k_vt(const unsigned short* __restrict__ QKV,
                                            unsigned short* __restrict__ VbT) {
    __shared__ alignas(16) unsigned short tile[64][72];
    int j = blockIdx.x;
    int r0 = (j >> 3) * 64, c0 = (j & 7) * 64;
    int tid = threadIdx.x;
    for (int k = 0; k < 2; ++k) {
        int c = tid + k * 256;
        int row = c >> 3, c8 = (c & 7) * 8;
        *(uint4*)&tile[row][c8] =
            *(const uint4*)(QKV + (size_t)(r0 + row) * 3072 + 2560 + c0 + c8);
    }
    __syncthreads();
    for (int k = 0; k < 2; ++k) {
        int c = tid + k * 256;
        int col = c >> 3, r8 = (c & 7) * 8;
        unsigned short t[8];
        for (int jj = 0; jj < 8; ++jj) t[jj] = tile[r8 + jj][col];
        *(uint4*)(VbT + (size_t)(c0 + col) * 8192 + r0 + r8) = *(const uint4*)t;
    }
}

// ---------------------------------------------------------------------------
// 2-phase double-buffered m97 GEMM, BK=64 / linear mapping / XOR swizzle all
// LOCKED (rounds 8/9/11 A/Bs). ROPE template (QKV only): table-driven rope
// in the bf16 epilogue (round-13 verified: no spill, bit-identical).
// ---------------------------------------------------------------------------
template <int ROPE>
__global__ __launch_bounds__(256) void k_gemm2ph(const unsigned short* __restrict__ A,
                                                 const unsigned short* __restrict__ Bt,
                                                 void* __restrict__ Cmat,
                                                 int M, int N, int K, int outF,
                                                 const float2* __restrict__ tab) {
    __shared__ union SM {
        struct { unsigned short A[2][128][64]; unsigned short B[2][128][64]; } s;  // 64 KB
        unsigned short ct[32][136];
        float          ctf[32][136];
    } sm;
    int tid = threadIdx.x;
    int w = tid >> 6, lane = tid & 63, quad = lane >> 4, l15 = lane & 15;
    int m0 = blockIdx.y * 128, n0 = blockIdx.x * 128;
    int wm = (w >> 1) * 64, wn = (w & 1) * 64;

    int srow   = lane >> 3;                 // 0..7
    int schunk = (lane & 7) ^ (lane >> 3);  // inverse-swizzled source chunk

    facc acc[4][4];
#pragma unroll
    for (int mi = 0; mi < 4; ++mi)
#pragma unroll
        for (int ni = 0; ni < 4; ++ni)
#pragma unroll
            for (int r = 0; r < 4; ++r) acc[mi][ni][r] = 0.f;

    auto stage = [&](int bb, int k0) {
#pragma unroll
        for (int i = 0; i < 4; ++i) {
            int row = w * 32 + i * 8;
            gl_lds16(A  + (size_t)(m0 + row + srow) * K + k0 + schunk * 8, &sm.s.A[bb][row][0]);
            gl_lds16(Bt + (size_t)(n0 + row + srow) * K + k0 + schunk * 8, &sm.s.B[bb][row][0]);
        }
    };

    int NT = K >> 6;
    stage(0, 0);
    __syncthreads();                        // implicit vmcnt(0): buf0 ready

    for (int t = 0; t < NT; ++t) {
        int cur = t & 1;
        if (t + 1 < NT) stage(cur ^ 1, (t + 1) * 64);   // hide under compute

        bfrag af[4][2], bf[4][2];
#pragma unroll
        for (int mi = 0; mi < 4; ++mi)
#pragma unroll
            for (int kc = 0; kc < 2; ++kc)
                af[mi][kc] = *(const bfrag*)&sm.s.A[cur][wm + mi * 16 + l15][((kc * 4 + quad) ^ (l15 & 7)) * 8];
#pragma unroll
        for (int ni = 0; ni < 4; ++ni)
#pragma unroll
            for (int kc = 0; kc < 2; ++kc)
                bf[ni][kc] = *(const bfrag*)&sm.s.B[cur][wn + ni * 16 + l15][((kc * 4 + quad) ^ (l15 & 7)) * 8];
#pragma unroll
        for (int kc = 0; kc < 2; ++kc)
#pragma unroll
            for (int mi = 0; mi < 4; ++mi)
#pragma unroll
                for (int ni = 0; ni < 4; ++ni)
                    acc[mi][ni] = __builtin_amdgcn_mfma_f32_16x16x32_bf16(af[mi][kc], bf[ni][kc], acc[mi][ni], 0, 0, 0);

        __syncthreads();                    // drains vmcnt (t+1 staged) + fences buf[cur]
    }

    // epilogue: 4 rounds; round t stages every wave's mi=t subtile (32x128)
#pragma unroll
    for (int t = 0; t < 4; ++t) {
        __syncthreads();
#pragma unroll
        for (int ni = 0; ni < 4; ++ni)
#pragma unroll
            for (int r = 0; r < 4; ++r) {
                int lr = (w >> 1) * 16 + quad * 4 + r;
                int lc = wn + ni * 16 + l15;
                if (outF) sm.ctf[lr][lc] = acc[t][ni][r];
                else      sm.ct [lr][lc] = f2b(acc[t][ni][r]);
            }
        __syncthreads();
        if (outF) {
#pragma unroll
            for (int i = 0; i < 4; ++i) {
                int cc = tid + i * 256;
                int lr = cc >> 5, c4 = (cc & 31) * 4;
                int grow = m0 + (lr >> 4) * 64 + t * 16 + (lr & 15);
                *(float4*)((float*)Cmat + (size_t)grow * N + n0 + c4) =
                    *(const float4*)&sm.ctf[lr][c4];
            }
        } else {
#pragma unroll
            for (int i = 0; i < 2; ++i) {
                int cc = tid + i * 256;
                int lr = cc >> 4, c8 = (cc & 15) * 8;
                int grow = m0 + (lr >> 4) * 64 + t * 16 + (lr & 15);
                uint4 val = *(const uint4*)&sm.ct[lr][c8];
                if constexpr (ROPE) {
                    if (n0 < 2560) {                  // block-uniform guard
                        unsigned short prt[8];
                        *(uint4*)prt = *(const uint4*)&sm.ct[lr][c8 ^ 64];
                        unsigned short* sp = (unsigned short*)&val;
                        int tt = grow & (TT - 1);
                        int d = (n0 + c8) & 127;      // heads are 128-aligned
                        int hi = d & 64;
                        const float2* tb = tab + tt * 64 + ((d & 63) >> 1) + (hi ? 32 : 0);
                        float2 cs0 = tb[0], cs1 = tb[1], cs2 = tb[2], cs3 = tb[3];
                        float2 cs[4] = {cs0, cs1, cs2, cs3};
#pragma unroll
                        for (int j = 0; j < 8; ++j) {
                            float a = b2f(sp[j]), bq = b2f(prt[j]);
                            float c = cs[j >> 1].x, s = cs[j >> 1].y;
                            sp[j] = f2b(hi ? (a * c + bq * s) : (a * c - bq * s));
                        }
                    }
                }
                *(uint4*)((unsigned short*)Cmat + (size_t)grow * N + n0 + c8) = val;
            }
        }
    }
}

// ---------------------------------------------------------------------------
// Flash attention, causal, GQA. Round-7/10/12 measured-good structure;
// THIS ROUND: P-path and final-output bf16 conversion moved from manual f2b
// (4 VALU each) to hardware v_cvt_pk_bf16_f32 (T12 context, m214-v22 pattern;
// RNE == f2b for finite inputs, P=exp()<=1 and O finite). Cuts softmax VALU
// per K-step ~65 -> ~37 ops.
// ---------------------------------------------------------------------------
__device__ __forceinline__ void flash_pass(
    int qbase, int b, int h, int kvh,
    const unsigned short* __restrict__ QKV,
    const unsigned short* __restrict__ VbT,
    unsigned short* __restrict__ att,
    unsigned short (&Ks)[2][32][136],
    unsigned short (&Vt)[2][128][40],
    unsigned short (&Pt)[8][16][40]) {

    int tid = threadIdx.x;
    int w = tid >> 6, lane = tid & 63, quad = lane >> 4, l15 = lane & 15;

    bfrag qf[4];
    {
        size_t qrow = (size_t)(b * TT + qbase + w * 16 + l15);
        for (int kc = 0; kc < 4; ++kc)
            qf[kc] = *(const bfrag*)(QKV + qrow * 3072 + h * 128 + kc * 32 + quad * 8);
    }

    float mreg = NEG_BIG, lreg = 0.f;      // state for q = qgmin + l15
    facc o[8];
#pragma unroll
    for (int nb2 = 0; nb2 < 8; ++nb2)
#pragma unroll
        for (int r = 0; r < 4; ++r) o[nb2][r] = 0.f;

    int krow = tid >> 4, d8 = (tid & 15) * 8;
    int vd = tid >> 2, tc = (tid & 3) * 8;
    const unsigned short* Kg = QKV + (size_t)(b * TT) * 3072 + 2048 + kvh * 128;
    const unsigned short* Vg = VbT + (size_t)(kvh * 128 + vd) * 8192 + b * TT;

    const float sc = 0.08838834764831845f;   // 1/sqrt(128)
    int kmax = qbase + 128;
    int nt = kmax >> 5;
    int qgmin = qbase + w * 16;
    int myq = qgmin + l15;                   // this lane's q-row

    uint4 rk = *(const uint4*)(Kg + (size_t)krow * 3072 + d8);
    uint4 rv = *(const uint4*)(Vg + tc);

    for (int t = 0; t < nt; ++t) {
        int cur = t & 1;
        int k0 = t * 32;
        *(uint4*)&Ks[cur][krow][d8] = rk;
        *(uint4*)&Vt[cur][vd][tc]   = rv;
        __syncthreads();

        if (t + 1 < nt) {
            int k0n = k0 + 32;
            rk = *(const uint4*)(Kg + (size_t)(k0n + krow) * 3072 + d8);
            rv = *(const uint4*)(Vg + k0n + tc);
        }

        if (k0 > qgmin + 15) continue;       // fully-masked tile for this wave

        // swapped QK^T: A = K-frag, B = Q-frag -> D[k][q], q = l15
        facc s[2];
#pragma unroll
        for (int nb = 0; nb < 2; ++nb) {
#pragma unroll
            for (int r = 0; r < 4; ++r) s[nb][r] = 0.f;
#pragma unroll
            for (int kc = 0; kc < 4; ++kc) {
                bfrag kf = *(const bfrag*)&Ks[cur][nb * 16 + l15][kc * 32 + quad * 8];
                s[nb] = __builtin_amdgcn_mfma_f32_16x16x32_bf16(kf, qf[kc], s[nb], 0, 0, 0);
            }
        }

        bool fullT = (k0 + 31) <= qgmin;
        float v[2][4];
        if (fullT) {
#pragma unroll
            for (int nb = 0; nb < 2; ++nb)
#pragma unroll
                for (int r = 0; r < 4; ++r) v[nb][r] = s[nb][r] * sc;
        } else {
#pragma unroll
            for (int nb = 0; nb < 2; ++nb)
#pragma unroll
                for (int r = 0; r < 4; ++r) {
                    int kg = k0 + nb * 16 + quad * 4 + r;
                    v[nb][r] = (kg > myq) ? NEG_BIG : s[nb][r] * sc;
                }
        }

        // row max: 7 local fmax + 2-step fold
        float mx = fmaxf(fmaxf(fmaxf(v[0][0], v[0][1]), fmaxf(v[0][2], v[0][3])),
                         fmaxf(fmaxf(v[1][0], v[1][1]), fmaxf(v[1][2], v[1][3])));
        mx = fmaxf(mx, __shfl_xor(mx, 16, 64));
        mx = fmaxf(mx, __shfl_xor(mx, 32, 64));

        bool need = (mx > mreg + 8.f);       // T13 defer-max, THR=8
        float mnew = need ? mx : mreg;
        float alpha = need ? __expf(mreg - mnew) : 1.f;

        float p[2][4];
        float psum = 0.f;
#pragma unroll
        for (int nb = 0; nb < 2; ++nb)
#pragma unroll
            for (int r = 0; r < 4; ++r) {
                p[nb][r] = __expf(v[nb][r] - mnew);   // exp(-huge)=0 for masked
                psum += p[nb][r];
            }
        psum += __shfl_xor(psum, 16, 64);
        psum += __shfl_xor(psum, 32, 64);
        lreg = lreg * alpha + psum;
        mreg = mnew;

        // P -> LDS via packed HW convert (4 cvt_pk replace 8 f2b = 32 VALU)
#pragma unroll
        for (int nb = 0; nb < 2; ++nb) {
            uint2 pk2;
            pk2.x = cvtpk_bf16(p[nb][0], p[nb][1]);
            pk2.y = cvtpk_bf16(p[nb][2], p[nb][3]);
            *(uint2*)&Pt[w][l15][nb * 16 + quad * 4] = pk2;
        }

        if (__any(need)) {                   // fetch per-q alpha, rescale o
#pragma unroll
            for (int r = 0; r < 4; ++r) {
                float al = __shfl(alpha, quad * 4 + r, 16);
#pragma unroll
                for (int nb2 = 0; nb2 < 8; ++nb2) o[nb2][r] *= al;
            }
        }

        asm volatile("s_waitcnt lgkmcnt(0)" ::: "memory");   // wave-local RAW on Pt[w]
        bfrag pf = *(const bfrag*)&Pt[w][l15][quad * 8];
#pragma unroll
        for (int nb2 = 0; nb2 < 8; ++nb2) {
            bfrag vf = *(const bfrag*)&Vt[cur][nb2 * 16 + l15][quad * 8];
            o[nb2] = __builtin_amdgcn_mfma_f32_16x16x32_bf16(pf, vf, o[nb2], 0, 0, 0);
        }
    }

    // final: fetch per-q l via width-16 shfl, divide, packed convert, store
    float lr[4];
#pragma unroll
    for (int r = 0; r < 4; ++r) lr[r] = __shfl(lreg, quad * 4 + r, 16);
#pragma unroll
    for (int nb2 = 0; nb2 < 8; ++nb2) {
        unsigned int lo = cvtpk_bf16(o[nb2][0] / lr[0], o[nb2][1] / lr[1]);
        unsigned int hi = cvtpk_bf16(o[nb2][2] / lr[2], o[nb2][3] / lr[3]);
        unsigned short ov[4] = {(unsigned short)lo, (unsigned short)(lo >> 16),
                                (unsigned short)hi, (unsigned short)(hi >> 16)};
#pragma unroll
        for (int r = 0; r < 4; ++r) {
            int qg = qbase + w * 16 + quad * 4 + r;
            att[(size_t)(b * TT + qg) * 2048 + h * 128 + nb2 * 16 + l15] = ov[r];
        }
    }
}

__global__ __launch_bounds__(512, 4) void k_flash(const unsigned short* __restrict__ QKV,
                                                  const unsigned short* __restrict__ VbT,
                                                  unsigned short* __restrict__ att) {
    __shared__ alignas(16) unsigned short Ks[2][32][136];
    __shared__ alignas(16) unsigned short Vt[2][128][40];
    __shared__ alignas(16) unsigned short Pt[8][16][40];
    int bh = blockIdx.y;
    int b = bh >> 4, h = bh & 15;
    int kvh = h >> 2;
    int i = blockIdx.x;

    flash_pass(i * 128, b, h, kvh, QKV, VbT, att, Ks, Vt, Pt);
    __syncthreads();
    flash_pass((15 - i) * 128, b, h, kvh, QKV, VbT, att, Ks, Vt, Pt);
}

// ---------------------------------------------------------------------------
extern "C" void kernel_launch(void* const* d_in, const int* in_sizes, int n_in,
                              void* d_out, int out_size, void* d_ws, size_t ws_size,
                              hipStream_t stream) {
    const float* x  = (const float*)d_in[0];
    const float* Wq = (const float*)d_in[1];
    const float* Wk = (const float*)d_in[2];
    const float* Wv = (const float*)d_in[3];
    const float* Wo = (const float*)d_in[4];
    const int* pos  = (const int*)d_in[5];

    char* ws = (char*)d_ws;
    unsigned short* xb   = (unsigned short*)(ws + 0);          // 32 MB (8192x2048); reused as att out
    unsigned short* QKV  = (unsigned short*)(ws + 33554432);   // 48 MB (8192x3072)
    unsigned short* VbT  = (unsigned short*)(ws + 83886080);   //  8 MB (512x8192)
    unsigned short* WqT  = (unsigned short*)(ws + 92274688);   //  8 MB (2048x2048)
    unsigned short* WkvT = (unsigned short*)(ws + 100663296);  //  4 MB (1024x2048) -- contiguous with WqT
    unsigned short* WoT  = (unsigned short*)(ws + 104857600);  //  8 MB
    float2*         tab  = (float2*)(ws + 113246208);          //  1 MB rope trig table -> 114.25 MB

    // x convert + trig table + all weight transposes (one launch)
    k_pre<<<11264, 256, 0, stream>>>(x, xb, tab, pos, Wq, Wk, Wv, Wo, WqT, WkvT, WoT);

    // fused Q|K|V projection with table-driven rope in the epilogue
    k_gemm2ph<1><<<dim3(24, 64), 256, 0, stream>>>(xb, WqT, QKV, 8192, 3072, 2048, 0, tab);

    // V transpose for flash B-frag staging
    k_vt<<<1024, 256, 0, stream>>>(QKV, VbT);

    // causal GQA flash attention (swapped-QK softmax, cvt_pk P-path) -> xb
    k_flash<<<dim3(8, 64), 512, 0, stream>>>(QKV, VbT, xb);

    // output projection -> fp32 d_out
    k_gemm2ph<0><<<dim3(16, 64), 256, 0, stream>>>(xb, WoT, d_out, 8192, 2048, 2048, 1, nullptr);
}

// Round 15
// 551.100 us; speedup vs baseline: 1.0945x; 1.0072x over previous
//
#include <hip/hip_runtime.h>
#include <math.h>

#define TT 2048

typedef __attribute__((ext_vector_type(8))) short bfrag;   // 8 bf16 in 4 VGPRs
typedef __attribute__((ext_vector_type(4))) float facc;    // 4 fp32 acc

#define NEG_BIG (-1.0e30f)

typedef __attribute__((address_space(1))) const void gas_void;
typedef __attribute__((address_space(3))) void las_void;

__device__ __forceinline__ void gl_lds16(const void* g, void* l) {
    __builtin_amdgcn_global_load_lds((gas_void*)g, (las_void*)l, 16, 0, 0);
}

__device__ __forceinline__ unsigned short f2b(float f) {
    union { float f; unsigned int i; } v; v.f = f;
    unsigned int b = v.i;
    return (unsigned short)((b + 0x7FFFu + ((b >> 16) & 1u)) >> 16);  // RNE
}
__device__ __forceinline__ float b2f(unsigned short s) {
    union { unsigned int i; float f; } u; u.i = ((unsigned int)s) << 16; return u.f;
}
// HW packed fp32->bf16 RNE (bit-identical to f2b for finite values)
__device__ __forceinline__ unsigned int cvtpk_bf16(float lo, float hi) {
    unsigned int r;
    asm("v_cvt_pk_bf16_f32 %0, %1, %2" : "=v"(r) : "v"(lo), "v"(hi));
    return r;
}
__device__ __forceinline__ void cvt8_f32(const float* __restrict__ p, unsigned short* d) {
    float4 lo = *(const float4*)p, hi = *(const float4*)(p + 4);
    d[0] = f2b(lo.x); d[1] = f2b(lo.y); d[2] = f2b(lo.z); d[3] = f2b(lo.w);
    d[4] = f2b(hi.x); d[5] = f2b(hi.y); d[6] = f2b(hi.z); d[7] = f2b(hi.w);
}

// ---------------------------------------------------------------------------
// Merged preprocessing (one launch):
//   [0,8192):     fp32->bf16 convert of x
//   [8192,8704):  RoPE trig table
//   [8704,11264): all four weight transposes
// ---------------------------------------------------------------------------
__global__ __launch_bounds__(256) void k_pre(const float* __restrict__ x,
                                             unsigned short* __restrict__ xb,
                                             float2* __restrict__ tab,
                                             const int* __restrict__ posPtr,
                                             const float* __restrict__ Wq,
                                             const float* __restrict__ Wk,
                                             const float* __restrict__ Wv,
                                             const float* __restrict__ Wo,
                                             unsigned short* __restrict__ WqT,
                                             unsigned short* __restrict__ WkvT,
                                             unsigned short* __restrict__ WoT) {
    __shared__ alignas(16) unsigned short tile[64][72];
    int bi = blockIdx.x;
    if (bi < 8192) {
        int c = bi * 256 + threadIdx.x;          // n8 = 2097152 exact
        unsigned short t[8];
        cvt8_f32(x + (size_t)c * 8, t);
        *(uint4*)(xb + (size_t)c * 8) = *(const uint4*)t;
    } else if (bi < 8704) {
        int tid = (bi - 8192) * 256 + threadIdx.x;   // 131072 total
        int i1 = tid & 63, t = tid >> 6;
        float p = (float)(*posPtr + t);
        float f = exp2f(-(float)i1 * 0.20762050595278f);
        float th = p * f;
        tab[tid] = make_float2(cosf(th), sinf(th));
    } else {
        int i = bi - 8704;
        const float* W; unsigned short* WT; int N, bx, by;
        if (i < 1024)      { W = Wq; WT = WqT; N = 2048; bx = i & 31; by = i >> 5; }
        else if (i < 1280) { int j = i - 1024; W = Wk; WT = WkvT; N = 512; bx = j & 7; by = j >> 3; }
        else if (i < 1536) { int j = i - 1280; W = Wv; WT = WkvT + (size_t)512 * 2048; N = 512; bx = j & 7; by = j >> 3; }
        else               { int j = i - 1536; W = Wo; WT = WoT; N = 2048; bx = j & 31; by = j >> 5; }
        int r0 = by * 64, c0 = bx * 64;
        int tid = threadIdx.x;
        for (int k = 0; k < 2; ++k) {
            int c = tid + k * 256;
            int row = c >> 3, c8 = (c & 7) * 8;
            unsigned short t[8];
            cvt8_f32(W + (size_t)(r0 + row) * N + c0 + c8, t);
            *(uint4*)&tile[row][c8] = *(const uint4*)t;
        }
        __syncthreads();
        for (int k = 0; k < 2; ++k) {
            int c = tid + k * 256;
            int col = c >> 3, r8 = (c & 7) * 8;
            unsigned short t[8];
            for (int j = 0; j < 8; ++j) t[j] = tile[r8 + j][col];
            *(uint4*)(WT + (size_t)(c0 + col) * 2048 + r0 + r8) = *(const uint4*)t;
        }
    }
}

// ---------------------------------------------------------------------------
// 2-phase double-buffered m97 GEMM, BK=64 / linear mapping / XOR swizzle all
// LOCKED. ROPE template (QKV only):
//   n0 < 2560 : table-driven rope in the bf16 epilogue (round-13 verified)
//   n0 >= 2560: V-columns -- ALSO store the staged tile TRANSPOSED to VbT
//               (replaces the separate k_vt kernel; same 16B-store pattern).
// Round-t LDS rows = two contiguous 16-row runs (m0+t*16.., m0+64+t*16..),
// so each 8-row gather is one contiguous uint4 in VbT.
// ---------------------------------------------------------------------------
template <int ROPE>
__global__ __launch_bounds__(256) void k_gemm2ph(const unsigned short* __restrict__ A,
                                                 const unsigned short* __restrict__ Bt,
                                                 void* __restrict__ Cmat,
                                                 int M, int N, int K, int outF,
                                                 const float2* __restrict__ tab,
                                                 unsigned short* __restrict__ VbT) {
    __shared__ union SM {
        struct { unsigned short A[2][128][64]; unsigned short B[2][128][64]; } s;  // 64 KB
        unsigned short ct[32][136];
        float          ctf[32][136];
    } sm;
    int tid = threadIdx.x;
    int w = tid >> 6, lane = tid & 63, quad = lane >> 4, l15 = lane & 15;
    int m0 = blockIdx.y * 128, n0 = blockIdx.x * 128;
    int wm = (w >> 1) * 64, wn = (w & 1) * 64;

    int srow   = lane >> 3;                 // 0..7
    int schunk = (lane & 7) ^ (lane >> 3);  // inverse-swizzled source chunk

    facc acc[4][4];
#pragma unroll
    for (int mi = 0; mi < 4; ++mi)
#pragma unroll
        for (int ni = 0; ni < 4; ++ni)
#pragma unroll
            for (int r = 0; r < 4; ++r) acc[mi][ni][r] = 0.f;

    auto stage = [&](int bb, int k0) {
#pragma unroll
        for (int i = 0; i < 4; ++i) {
            int row = w * 32 + i * 8;
            gl_lds16(A  + (size_t)(m0 + row + srow) * K + k0 + schunk * 8, &sm.s.A[bb][row][0]);
            gl_lds16(Bt + (size_t)(n0 + row + srow) * K + k0 + schunk * 8, &sm.s.B[bb][row][0]);
        }
    };

    int NT = K >> 6;
    stage(0, 0);
    __syncthreads();                        // implicit vmcnt(0): buf0 ready

    for (int t = 0; t < NT; ++t) {
        int cur = t & 1;
        if (t + 1 < NT) stage(cur ^ 1, (t + 1) * 64);   // hide under compute

        bfrag af[4][2], bf[4][2];
#pragma unroll
        for (int mi = 0; mi < 4; ++mi)
#pragma unroll
            for (int kc = 0; kc < 2; ++kc)
                af[mi][kc] = *(const bfrag*)&sm.s.A[cur][wm + mi * 16 + l15][((kc * 4 + quad) ^ (l15 & 7)) * 8];
#pragma unroll
        for (int ni = 0; ni < 4; ++ni)
#pragma unroll
            for (int kc = 0; kc < 2; ++kc)
                bf[ni][kc] = *(const bfrag*)&sm.s.B[cur][wn + ni * 16 + l15][((kc * 4 + quad) ^ (l15 & 7)) * 8];
#pragma unroll
        for (int kc = 0; kc < 2; ++kc)
#pragma unroll
            for (int mi = 0; mi < 4; ++mi)
#pragma unroll
                for (int ni = 0; ni < 4; ++ni)
                    acc[mi][ni] = __builtin_amdgcn_mfma_f32_16x16x32_bf16(af[mi][kc], bf[ni][kc], acc[mi][ni], 0, 0, 0);

        __syncthreads();                    // drains vmcnt (t+1 staged) + fences buf[cur]
    }

    // epilogue: 4 rounds; round t stages every wave's mi=t subtile (32x128)
#pragma unroll
    for (int t = 0; t < 4; ++t) {
        __syncthreads();
#pragma unroll
        for (int ni = 0; ni < 4; ++ni)
#pragma unroll
            for (int r = 0; r < 4; ++r) {
                int lr = (w >> 1) * 16 + quad * 4 + r;
                int lc = wn + ni * 16 + l15;
                if (outF) sm.ctf[lr][lc] = acc[t][ni][r];
                else      sm.ct [lr][lc] = f2b(acc[t][ni][r]);
            }
        __syncthreads();
        if (outF) {
#pragma unroll
            for (int i = 0; i < 4; ++i) {
                int cc = tid + i * 256;
                int lr = cc >> 5, c4 = (cc & 31) * 4;
                int grow = m0 + (lr >> 4) * 64 + t * 16 + (lr & 15);
                *(float4*)((float*)Cmat + (size_t)grow * N + n0 + c4) =
                    *(const float4*)&sm.ctf[lr][c4];
            }
        } else {
#pragma unroll
            for (int i = 0; i < 2; ++i) {
                int cc = tid + i * 256;
                int lr = cc >> 4, c8 = (cc & 15) * 8;
                int grow = m0 + (lr >> 4) * 64 + t * 16 + (lr & 15);
                uint4 val = *(const uint4*)&sm.ct[lr][c8];
                if constexpr (ROPE) {
                    if (n0 < 2560) {                  // block-uniform guard
                        unsigned short prt[8];
                        *(uint4*)prt = *(const uint4*)&sm.ct[lr][c8 ^ 64];
                        unsigned short* sp = (unsigned short*)&val;
                        int tt = grow & (TT - 1);
                        int d = (n0 + c8) & 127;      // heads are 128-aligned
                        int hi = d & 64;
                        const float2* tb = tab + tt * 64 + ((d & 63) >> 1) + (hi ? 32 : 0);
                        float2 cs0 = tb[0], cs1 = tb[1], cs2 = tb[2], cs3 = tb[3];
                        float2 cs[4] = {cs0, cs1, cs2, cs3};
#pragma unroll
                        for (int j = 0; j < 8; ++j) {
                            float a = b2f(sp[j]), bq = b2f(prt[j]);
                            float c = cs[j >> 1].x, s = cs[j >> 1].y;
                            sp[j] = f2b(hi ? (a * c + bq * s) : (a * c - bq * s));
                        }
                    }
                }
                *(uint4*)((unsigned short*)Cmat + (size_t)grow * N + n0 + c8) = val;
            }
            if constexpr (ROPE) {
                if (n0 >= 2560) {
                    // fused V-transpose: VbT[(n0-2560+col)*8192 + rows]
#pragma unroll
                    for (int i = 0; i < 2; ++i) {
                        int cc = tid + i * 256;
                        int col = cc >> 2, rgrp = cc & 3;
                        int lr8 = rgrp * 8;
                        unsigned short t8[8];
#pragma unroll
                        for (int j = 0; j < 8; ++j) t8[j] = sm.ct[lr8 + j][col];
                        int growb = m0 + ((lr8 & 16) ? 64 : 0) + t * 16 + (lr8 & 15);
                        *(uint4*)(VbT + (size_t)(n0 - 2560 + col) * 8192 + growb) =
                            *(const uint4*)t8;
                    }
                }
            }
        }
    }
}

// ---------------------------------------------------------------------------
// Flash attention, causal, GQA (locked config): 512 threads, QBLK=128,
// paired q-tiles (i, 15-i); double-buffered K/V LDS, one barrier per K-step,
// register prefetch post-barrier; inactive-tile skip; interior fast path;
// T13 defer-max THR=8; swapped QK^T softmax; cvt_pk P/O conversion.
// ---------------------------------------------------------------------------
__device__ __forceinline__ void flash_pass(
    int qbase, int b, int h, int kvh,
    const unsigned short* __restrict__ QKV,
    const unsigned short* __restrict__ VbT,
    unsigned short* __restrict__ att,
    unsigned short (&Ks)[2][32][136],
    unsigned short (&Vt)[2][128][40],
    unsigned short (&Pt)[8][16][40]) {

    int tid = threadIdx.x;
    int w = tid >> 6, lane = tid & 63, quad = lane >> 4, l15 = lane & 15;

    bfrag qf[4];
    {
        size_t qrow = (size_t)(b * TT + qbase + w * 16 + l15);
        for (int kc = 0; kc < 4; ++kc)
            qf[kc] = *(const bfrag*)(QKV + qrow * 3072 + h * 128 + kc * 32 + quad * 8);
    }

    float mreg = NEG_BIG, lreg = 0.f;      // state for q = qgmin + l15
    facc o[8];
#pragma unroll
    for (int nb2 = 0; nb2 < 8; ++nb2)
#pragma unroll
        for (int r = 0; r < 4; ++r) o[nb2][r] = 0.f;

    int krow = tid >> 4, d8 = (tid & 15) * 8;
    int vd = tid >> 2, tc = (tid & 3) * 8;
    const unsigned short* Kg = QKV + (size_t)(b * TT) * 3072 + 2048 + kvh * 128;
    const unsigned short* Vg = VbT + (size_t)(kvh * 128 + vd) * 8192 + b * TT;

    const float sc = 0.08838834764831845f;   // 1/sqrt(128)
    int kmax = qbase + 128;
    int nt = kmax >> 5;
    int qgmin = qbase + w * 16;
    int myq = qgmin + l15;                   // this lane's q-row

    uint4 rk = *(const uint4*)(Kg + (size_t)krow * 3072 + d8);
    uint4 rv = *(const uint4*)(Vg + tc);

    for (int t = 0; t < nt; ++t) {
        int cur = t & 1;
        int k0 = t * 32;
        *(uint4*)&Ks[cur][krow][d8] = rk;
        *(uint4*)&Vt[cur][vd][tc]   = rv;
        __syncthreads();

        if (t + 1 < nt) {
            int k0n = k0 + 32;
            rk = *(const uint4*)(Kg + (size_t)(k0n + krow) * 3072 + d8);
            rv = *(const uint4*)(Vg + k0n + tc);
        }

        if (k0 > qgmin + 15) continue;       // fully-masked tile for this wave

        // swapped QK^T: A = K-frag, B = Q-frag -> D[k][q], q = l15
        facc s[2];
#pragma unroll
        for (int nb = 0; nb < 2; ++nb) {
#pragma unroll
            for (int r = 0; r < 4; ++r) s[nb][r] = 0.f;
#pragma unroll
            for (int kc = 0; kc < 4; ++kc) {
                bfrag kf = *(const bfrag*)&Ks[cur][nb * 16 + l15][kc * 32 + quad * 8];
                s[nb] = __builtin_amdgcn_mfma_f32_16x16x32_bf16(kf, qf[kc], s[nb], 0, 0, 0);
            }
        }

        bool fullT = (k0 + 31) <= qgmin;
        float v[2][4];
        if (fullT) {
#pragma unroll
            for (int nb = 0; nb < 2; ++nb)
#pragma unroll
                for (int r = 0; r < 4; ++r) v[nb][r] = s[nb][r] * sc;
        } else {
#pragma unroll
            for (int nb = 0; nb < 2; ++nb)
#pragma unroll
                for (int r = 0; r < 4; ++r) {
                    int kg = k0 + nb * 16 + quad * 4 + r;
                    v[nb][r] = (kg > myq) ? NEG_BIG : s[nb][r] * sc;
                }
        }

        // row max: 7 local fmax + 2-step fold
        float mx = fmaxf(fmaxf(fmaxf(v[0][0], v[0][1]), fmaxf(v[0][2], v[0][3])),
                         fmaxf(fmaxf(v[1][0], v[1][1]), fmaxf(v[1][2], v[1][3])));
        mx = fmaxf(mx, __shfl_xor(mx, 16, 64));
        mx = fmaxf(mx, __shfl_xor(mx, 32, 64));

        bool need = (mx > mreg + 8.f);       // T13 defer-max, THR=8
        float mnew = need ? mx : mreg;
        float alpha = need ? __expf(mreg - mnew) : 1.f;

        float p[2][4];
        float psum = 0.f;
#pragma unroll
        for (int nb = 0; nb < 2; ++nb)
#pragma unroll
            for (int r = 0; r < 4; ++r) {
                p[nb][r] = __expf(v[nb][r] - mnew);   // exp(-huge)=0 for masked
                psum += p[nb][r];
            }
        psum += __shfl_xor(psum, 16, 64);
        psum += __shfl_xor(psum, 32, 64);
        lreg = lreg * alpha + psum;
        mreg = mnew;

        // P -> LDS via packed HW convert
#pragma unroll
        for (int nb = 0; nb < 2; ++nb) {
            uint2 pk2;
            pk2.x = cvtpk_bf16(p[nb][0], p[nb][1]);
            pk2.y = cvtpk_bf16(p[nb][2], p[nb][3]);
            *(uint2*)&Pt[w][l15][nb * 16 + quad * 4] = pk2;
        }

        if (__any(need)) {                   // fetch per-q alpha, rescale o
#pragma unroll
            for (int r = 0; r < 4; ++r) {
                float al = __shfl(alpha, quad * 4 + r, 16);
#pragma unroll
                for (int nb2 = 0; nb2 < 8; ++nb2) o[nb2][r] *= al;
            }
        }

        asm volatile("s_waitcnt lgkmcnt(0)" ::: "memory");   // wave-local RAW on Pt[w]
        bfrag pf = *(const bfrag*)&Pt[w][l15][quad * 8];
#pragma unroll
        for (int nb2 = 0; nb2 < 8; ++nb2) {
            bfrag vf = *(const bfrag*)&Vt[cur][nb2 * 16 + l15][quad * 8];
            o[nb2] = __builtin_amdgcn_mfma_f32_16x16x32_bf16(pf, vf, o[nb2], 0, 0, 0);
        }
    }

    // final: fetch per-q l via width-16 shfl, divide, packed convert, store
    float lr[4];
#pragma unroll
    for (int r = 0; r < 4; ++r) lr[r] = __shfl(lreg, quad * 4 + r, 16);
#pragma unroll
    for (int nb2 = 0; nb2 < 8; ++nb2) {
        unsigned int lo = cvtpk_bf16(o[nb2][0] / lr[0], o[nb2][1] / lr[1]);
        unsigned int hi = cvtpk_bf16(o[nb2][2] / lr[2], o[nb2][3] / lr[3]);
        unsigned short ov[4] = {(unsigned short)lo, (unsigned short)(lo >> 16),
                                (unsigned short)hi, (unsigned short)(hi >> 16)};
#pragma unroll
        for (int r = 0; r < 4; ++r) {
            int qg = qbase + w * 16 + quad * 4 + r;
            att[(size_t)(b * TT + qg) * 2048 + h * 128 + nb2 * 16 + l15] = ov[r];
        }
    }
}

__global__ __launch_bounds__(512, 4) void k_flash(const unsigned short* __restrict__ QKV,
                                                  const unsigned short* __restrict__ VbT,
                                                  unsigned short* __restrict__ att) {
    __shared__ alignas(16) unsigned short Ks[2][32][136];
    __shared__ alignas(16) unsigned short Vt[2][128][40];
    __shared__ alignas(16) unsigned short Pt[8][16][40];
    int bh = blockIdx.y;
    int b = bh >> 4, h = bh & 15;
    int kvh = h >> 2;
    int i = blockIdx.x;

    flash_pass(i * 128, b, h, kvh, QKV, VbT, att, Ks, Vt, Pt);
    __syncthreads();
    flash_pass((15 - i) * 128, b, h, kvh, QKV, VbT, att, Ks, Vt, Pt);
}

// ---------------------------------------------------------------------------
extern "C" void kernel_launch(void* const* d_in, const int* in_sizes, int n_in,
                              void* d_out, int out_size, void* d_ws, size_t ws_size,
                              hipStream_t stream) {
    const float* x  = (const float*)d_in[0];
    const float* Wq = (const float*)d_in[1];
    const float* Wk = (const float*)d_in[2];
    const float* Wv = (const float*)d_in[3];
    const float* Wo = (const float*)d_in[4];
    const int* pos  = (const int*)d_in[5];

    char* ws = (char*)d_ws;
    unsigned short* xb   = (unsigned short*)(ws + 0);          // 32 MB (8192x2048); reused as att out
    unsigned short* QKV  = (unsigned short*)(ws + 33554432);   // 48 MB (8192x3072)
    unsigned short* VbT  = (unsigned short*)(ws + 83886080);   //  8 MB (512x8192)
    unsigned short* WqT  = (unsigned short*)(ws + 92274688);   //  8 MB (2048x2048)
    unsigned short* WkvT = (unsigned short*)(ws + 100663296);  //  4 MB (1024x2048) -- contiguous with WqT
    unsigned short* WoT  = (unsigned short*)(ws + 104857600);  //  8 MB
    float2*         tab  = (float2*)(ws + 113246208);          //  1 MB rope trig table -> 114.25 MB

    // x convert + trig table + all weight transposes (one launch)
    k_pre<<<11264, 256, 0, stream>>>(x, xb, tab, pos, Wq, Wk, Wv, Wo, WqT, WkvT, WoT);

    // fused Q|K|V projection: rope in epilogue (Q/K cols) + V-transpose to
    // VbT in epilogue (V cols) -- k_vt kernel deleted
    k_gemm2ph<1><<<dim3(24, 64), 256, 0, stream>>>(xb, WqT, QKV, 8192, 3072, 2048, 0, tab, VbT);

    // causal GQA flash attention (swapped-QK softmax, cvt_pk P-path) -> xb
    k_flash<<<dim3(8, 64), 512, 0, stream>>>(QKV, VbT, xb);

    // output projection -> fp32 d_out
    k_gemm2ph<0><<<dim3(16, 64), 256, 0, stream>>>(xb, WoT, d_out, 8192, 2048, 2048, 1, nullptr, nullptr);
}

// Round 16
// 538.663 us; speedup vs baseline: 1.1198x; 1.0231x over previous
//
#include <hip/hip_runtime.h>
#include <math.h>

#define TT 2048

typedef __attribute__((ext_vector_type(8))) short bfrag;   // 8 bf16 in 4 VGPRs
typedef __attribute__((ext_vector_type(4))) float facc;    // 4 fp32 acc

#define NEG_BIG (-1.0e30f)

typedef __attribute__((address_space(1))) const void gas_void;
typedef __attribute__((address_space(3))) void las_void;

__device__ __forceinline__ void gl_lds16(const void* g, void* l) {
    __builtin_amdgcn_global_load_lds((gas_void*)g, (las_void*)l, 16, 0, 0);
}

__device__ __forceinline__ unsigned short f2b(float f) {
    union { float f; unsigned int i; } v; v.f = f;
    unsigned int b = v.i;
    return (unsigned short)((b + 0x7FFFu + ((b >> 16) & 1u)) >> 16);  // RNE
}
__device__ __forceinline__ float b2f(unsigned short s) {
    union { unsigned int i; float f; } u; u.i = ((unsigned int)s) << 16; return u.f;
}
// HW packed fp32->bf16 RNE (bit-identical to f2b for finite values)
__device__ __forceinline__ unsigned int cvtpk_bf16(float lo, float hi) {
    unsigned int r;
    asm("v_cvt_pk_bf16_f32 %0, %1, %2" : "=v"(r) : "v"(lo), "v"(hi));
    return r;
}
// 8 fp32 -> 8 bf16 via 4 packed converts
__device__ __forceinline__ uint4 cvt8_pk(const float* __restrict__ p) {
    float4 lo = *(const float4*)p, hi = *(const float4*)(p + 4);
    uint4 r;
    r.x = cvtpk_bf16(lo.x, lo.y);
    r.y = cvtpk_bf16(lo.z, lo.w);
    r.z = cvtpk_bf16(hi.x, hi.y);
    r.w = cvtpk_bf16(hi.z, hi.w);
    return r;
}

// ---------------------------------------------------------------------------
// Merged preprocessing (one launch):
//   [0,8192):     fp32->bf16 convert of x
//   [8192,8704):  RoPE trig table
//   [8704,11264): all four weight transposes
// ---------------------------------------------------------------------------
__global__ __launch_bounds__(256) void k_pre(const float* __restrict__ x,
                                             unsigned short* __restrict__ xb,
                                             float2* __restrict__ tab,
                                             const int* __restrict__ posPtr,
                                             const float* __restrict__ Wq,
                                             const float* __restrict__ Wk,
                                             const float* __restrict__ Wv,
                                             const float* __restrict__ Wo,
                                             unsigned short* __restrict__ WqT,
                                             unsigned short* __restrict__ WkvT,
                                             unsigned short* __restrict__ WoT) {
    __shared__ alignas(16) unsigned short tile[64][72];
    int bi = blockIdx.x;
    if (bi < 8192) {
        int c = bi * 256 + threadIdx.x;          // n8 = 2097152 exact
        *(uint4*)(xb + (size_t)c * 8) = cvt8_pk(x + (size_t)c * 8);
    } else if (bi < 8704) {
        int tid = (bi - 8192) * 256 + threadIdx.x;   // 131072 total
        int i1 = tid & 63, t = tid >> 6;
        float p = (float)(*posPtr + t);
        float f = exp2f(-(float)i1 * 0.20762050595278f);
        float th = p * f;
        tab[tid] = make_float2(cosf(th), sinf(th));
    } else {
        int i = bi - 8704;
        const float* W; unsigned short* WT; int N, bx, by;
        if (i < 1024)      { W = Wq; WT = WqT; N = 2048; bx = i & 31; by = i >> 5; }
        else if (i < 1280) { int j = i - 1024; W = Wk; WT = WkvT; N = 512; bx = j & 7; by = j >> 3; }
        else if (i < 1536) { int j = i - 1280; W = Wv; WT = WkvT + (size_t)512 * 2048; N = 512; bx = j & 7; by = j >> 3; }
        else               { int j = i - 1536; W = Wo; WT = WoT; N = 2048; bx = j & 31; by = j >> 5; }
        int r0 = by * 64, c0 = bx * 64;
        int tid = threadIdx.x;
        for (int k = 0; k < 2; ++k) {
            int c = tid + k * 256;
            int row = c >> 3, c8 = (c & 7) * 8;
            *(uint4*)&tile[row][c8] = cvt8_pk(W + (size_t)(r0 + row) * N + c0 + c8);
        }
        __syncthreads();
        for (int k = 0; k < 2; ++k) {
            int c = tid + k * 256;
            int col = c >> 3, r8 = (c & 7) * 8;
            unsigned short t[8];
            for (int j = 0; j < 8; ++j) t[j] = tile[r8 + j][col];
            *(uint4*)(WT + (size_t)(c0 + col) * 2048 + r0 + r8) = *(const uint4*)t;
        }
    }
}

// ---------------------------------------------------------------------------
// 2-phase double-buffered m97 GEMM, BK=64 / linear mapping / XOR swizzle all
// LOCKED. ROPE template (QKV only):
//   n0 < 2560 : table-driven rope in the bf16 epilogue (round-13 verified)
//   n0 >= 2560: fused V-transpose to VbT (round-15 verified)
// ---------------------------------------------------------------------------
template <int ROPE>
__global__ __launch_bounds__(256) void k_gemm2ph(const unsigned short* __restrict__ A,
                                                 const unsigned short* __restrict__ Bt,
                                                 void* __restrict__ Cmat,
                                                 int M, int N, int K, int outF,
                                                 const float2* __restrict__ tab,
                                                 unsigned short* __restrict__ VbT) {
    __shared__ union SM {
        struct { unsigned short A[2][128][64]; unsigned short B[2][128][64]; } s;  // 64 KB
        unsigned short ct[32][136];
        float          ctf[32][136];
    } sm;
    int tid = threadIdx.x;
    int w = tid >> 6, lane = tid & 63, quad = lane >> 4, l15 = lane & 15;
    int m0 = blockIdx.y * 128, n0 = blockIdx.x * 128;
    int wm = (w >> 1) * 64, wn = (w & 1) * 64;

    int srow   = lane >> 3;                 // 0..7
    int schunk = (lane & 7) ^ (lane >> 3);  // inverse-swizzled source chunk

    facc acc[4][4];
#pragma unroll
    for (int mi = 0; mi < 4; ++mi)
#pragma unroll
        for (int ni = 0; ni < 4; ++ni)
#pragma unroll
            for (int r = 0; r < 4; ++r) acc[mi][ni][r] = 0.f;

    auto stage = [&](int bb, int k0) {
#pragma unroll
        for (int i = 0; i < 4; ++i) {
            int row = w * 32 + i * 8;
            gl_lds16(A  + (size_t)(m0 + row + srow) * K + k0 + schunk * 8, &sm.s.A[bb][row][0]);
            gl_lds16(Bt + (size_t)(n0 + row + srow) * K + k0 + schunk * 8, &sm.s.B[bb][row][0]);
        }
    };

    int NT = K >> 6;
    stage(0, 0);
    __syncthreads();                        // implicit vmcnt(0): buf0 ready

    for (int t = 0; t < NT; ++t) {
        int cur = t & 1;
        if (t + 1 < NT) stage(cur ^ 1, (t + 1) * 64);   // hide under compute

        bfrag af[4][2], bf[4][2];
#pragma unroll
        for (int mi = 0; mi < 4; ++mi)
#pragma unroll
            for (int kc = 0; kc < 2; ++kc)
                af[mi][kc] = *(const bfrag*)&sm.s.A[cur][wm + mi * 16 + l15][((kc * 4 + quad) ^ (l15 & 7)) * 8];
#pragma unroll
        for (int ni = 0; ni < 4; ++ni)
#pragma unroll
            for (int kc = 0; kc < 2; ++kc)
                bf[ni][kc] = *(const bfrag*)&sm.s.B[cur][wn + ni * 16 + l15][((kc * 4 + quad) ^ (l15 & 7)) * 8];
#pragma unroll
        for (int kc = 0; kc < 2; ++kc)
#pragma unroll
            for (int mi = 0; mi < 4; ++mi)
#pragma unroll
                for (int ni = 0; ni < 4; ++ni)
                    acc[mi][ni] = __builtin_amdgcn_mfma_f32_16x16x32_bf16(af[mi][kc], bf[ni][kc], acc[mi][ni], 0, 0, 0);

        __syncthreads();                    // drains vmcnt (t+1 staged) + fences buf[cur]
    }

    // epilogue: 4 rounds; round t stages every wave's mi=t subtile (32x128)
#pragma unroll
    for (int t = 0; t < 4; ++t) {
        __syncthreads();
#pragma unroll
        for (int ni = 0; ni < 4; ++ni)
#pragma unroll
            for (int r = 0; r < 4; ++r) {
                int lr = (w >> 1) * 16 + quad * 4 + r;
                int lc = wn + ni * 16 + l15;
                if (outF) sm.ctf[lr][lc] = acc[t][ni][r];
                else      sm.ct [lr][lc] = f2b(acc[t][ni][r]);
            }
        __syncthreads();
        if (outF) {
#pragma unroll
            for (int i = 0; i < 4; ++i) {
                int cc = tid + i * 256;
                int lr = cc >> 5, c4 = (cc & 31) * 4;
                int grow = m0 + (lr >> 4) * 64 + t * 16 + (lr & 15);
                *(float4*)((float*)Cmat + (size_t)grow * N + n0 + c4) =
                    *(const float4*)&sm.ctf[lr][c4];
            }
        } else {
#pragma unroll
            for (int i = 0; i < 2; ++i) {
                int cc = tid + i * 256;
                int lr = cc >> 4, c8 = (cc & 15) * 8;
                int grow = m0 + (lr >> 4) * 64 + t * 16 + (lr & 15);
                uint4 val = *(const uint4*)&sm.ct[lr][c8];
                if constexpr (ROPE) {
                    if (n0 < 2560) {                  // block-uniform guard
                        unsigned short prt[8];
                        *(uint4*)prt = *(const uint4*)&sm.ct[lr][c8 ^ 64];
                        unsigned short* sp = (unsigned short*)&val;
                        unsigned int* vi = (unsigned int*)&val;
                        int tt = grow & (TT - 1);
                        int d = (n0 + c8) & 127;      // heads are 128-aligned
                        int hi = d & 64;
                        const float2* tb = tab + tt * 64 + ((d & 63) >> 1) + (hi ? 32 : 0);
                        float2 cs0 = tb[0], cs1 = tb[1], cs2 = tb[2], cs3 = tb[3];
                        float2 cs[4] = {cs0, cs1, cs2, cs3};
#pragma unroll
                        for (int j2 = 0; j2 < 4; ++j2) {
                            float a0 = b2f(sp[j2 * 2]),     bq0 = b2f(prt[j2 * 2]);
                            float a1 = b2f(sp[j2 * 2 + 1]), bq1 = b2f(prt[j2 * 2 + 1]);
                            float c = cs[j2].x, s = cs[j2].y;
                            float r0 = hi ? (a0 * c + bq0 * s) : (a0 * c - bq0 * s);
                            float r1 = hi ? (a1 * c + bq1 * s) : (a1 * c - bq1 * s);
                            vi[j2] = cvtpk_bf16(r0, r1);
                        }
                    }
                }
                *(uint4*)((unsigned short*)Cmat + (size_t)grow * N + n0 + c8) = val;
            }
            if constexpr (ROPE) {
                if (n0 >= 2560) {
                    // fused V-transpose: VbT[(n0-2560+col)*8192 + rows]
#pragma unroll
                    for (int i = 0; i < 2; ++i) {
                        int cc = tid + i * 256;
                        int col = cc >> 2, rgrp = cc & 3;
                        int lr8 = rgrp * 8;
                        unsigned short t8[8];
#pragma unroll
                        for (int j = 0; j < 8; ++j) t8[j] = sm.ct[lr8 + j][col];
                        int growb = m0 + ((lr8 & 16) ? 64 : 0) + t * 16 + (lr8 & 15);
                        *(uint4*)(VbT + (size_t)(n0 - 2560 + col) * 8192 + growb) =
                            *(const uint4*)t8;
                    }
                }
            }
        }
    }
}

// ---------------------------------------------------------------------------
// Flash attention, causal, GQA. Locked structure; THIS ROUND the softmax
// cross-lane chain is cut (round-14 lesson: chain latency, not op count):
//   - sum-fold DEFERRED: lreg is a per-lane partial (own 8 k-slots); the 4
//     lanes sharing a q-row (same l15) hold identical mreg/alpha, so the
//     cross-lane fold moves to once-per-pass (was 2 shfl_xor per K-step).
//   - max-fold CONDITIONAL: gated behind __any(local_mx > mreg+8) -- same
//     trigger as the folded check (max of locals exceeds iff some local
//     does). Common path: 7 fmax + wave-any, ZERO shuffles. Rare path
//     (first tile, rare growth): fold + rescale, bit-identical to before.
// Only FP summation order of l changes (positive terms; ~1e-7 relative).
// ---------------------------------------------------------------------------
__device__ __forceinline__ void flash_pass(
    int qbase, int b, int h, int kvh,
    const unsigned short* __restrict__ QKV,
    const unsigned short* __restrict__ VbT,
    unsigned short* __restrict__ att,
    unsigned short (&Ks)[2][32][136],
    unsigned short (&Vt)[2][128][40],
    unsigned short (&Pt)[8][16][40]) {

    int tid = threadIdx.x;
    int w = tid >> 6, lane = tid & 63, quad = lane >> 4, l15 = lane & 15;

    bfrag qf[4];
    {
        size_t qrow = (size_t)(b * TT + qbase + w * 16 + l15);
        for (int kc = 0; kc < 4; ++kc)
            qf[kc] = *(const bfrag*)(QKV + qrow * 3072 + h * 128 + kc * 32 + quad * 8);
    }

    float mreg = NEG_BIG, lreg = 0.f;      // per-lane partial state, q = qgmin+l15
    facc o[8];
#pragma unroll
    for (int nb2 = 0; nb2 < 8; ++nb2)
#pragma unroll
        for (int r = 0; r < 4; ++r) o[nb2][r] = 0.f;

    int krow = tid >> 4, d8 = (tid & 15) * 8;
    int vd = tid >> 2, tc = (tid & 3) * 8;
    const unsigned short* Kg = QKV + (size_t)(b * TT) * 3072 + 2048 + kvh * 128;
    const unsigned short* Vg = VbT + (size_t)(kvh * 128 + vd) * 8192 + b * TT;

    const float sc = 0.08838834764831845f;   // 1/sqrt(128)
    int kmax = qbase + 128;
    int nt = kmax >> 5;
    int qgmin = qbase + w * 16;
    int myq = qgmin + l15;                   // this lane's q-row

    uint4 rk = *(const uint4*)(Kg + (size_t)krow * 3072 + d8);
    uint4 rv = *(const uint4*)(Vg + tc);

    for (int t = 0; t < nt; ++t) {
        int cur = t & 1;
        int k0 = t * 32;
        *(uint4*)&Ks[cur][krow][d8] = rk;
        *(uint4*)&Vt[cur][vd][tc]   = rv;
        __syncthreads();

        if (t + 1 < nt) {
            int k0n = k0 + 32;
            rk = *(const uint4*)(Kg + (size_t)(k0n + krow) * 3072 + d8);
            rv = *(const uint4*)(Vg + k0n + tc);
        }

        if (k0 > qgmin + 15) continue;       // fully-masked tile for this wave

        // swapped QK^T: A = K-frag, B = Q-frag -> D[k][q], q = l15
        facc s[2];
#pragma unroll
        for (int nb = 0; nb < 2; ++nb) {
#pragma unroll
            for (int r = 0; r < 4; ++r) s[nb][r] = 0.f;
#pragma unroll
            for (int kc = 0; kc < 4; ++kc) {
                bfrag kf = *(const bfrag*)&Ks[cur][nb * 16 + l15][kc * 32 + quad * 8];
                s[nb] = __builtin_amdgcn_mfma_f32_16x16x32_bf16(kf, qf[kc], s[nb], 0, 0, 0);
            }
        }

        bool fullT = (k0 + 31) <= qgmin;
        float v[2][4];
        if (fullT) {
#pragma unroll
            for (int nb = 0; nb < 2; ++nb)
#pragma unroll
                for (int r = 0; r < 4; ++r) v[nb][r] = s[nb][r] * sc;
        } else {
#pragma unroll
            for (int nb = 0; nb < 2; ++nb)
#pragma unroll
                for (int r = 0; r < 4; ++r) {
                    int kg = k0 + nb * 16 + quad * 4 + r;
                    v[nb][r] = (kg > myq) ? NEG_BIG : s[nb][r] * sc;
                }
        }

        // local row max (7 fmax), NO shuffles on the common path
        float mx = fmaxf(fmaxf(fmaxf(v[0][0], v[0][1]), fmaxf(v[0][2], v[0][3])),
                         fmaxf(fmaxf(v[1][0], v[1][1]), fmaxf(v[1][2], v[1][3])));

        if (__any(mx > mreg + 8.f)) {        // rare path: fold + rescale
            float fmx = fmaxf(mx, __shfl_xor(mx, 16, 64));
            fmx = fmaxf(fmx, __shfl_xor(fmx, 32, 64));
            bool need = (fmx > mreg + 8.f);
            float mnew = need ? fmx : mreg;
            float alpha = need ? __expf(mreg - mnew) : 1.f;
            lreg *= alpha;
            mreg = mnew;
#pragma unroll
            for (int r = 0; r < 4; ++r) {
                float al = __shfl(alpha, quad * 4 + r, 16);
#pragma unroll
                for (int nb2 = 0; nb2 < 8; ++nb2) o[nb2][r] *= al;
            }
        }

        float p[2][4];
        float lsum = 0.f;
#pragma unroll
        for (int nb = 0; nb < 2; ++nb)
#pragma unroll
            for (int r = 0; r < 4; ++r) {
                p[nb][r] = __expf(v[nb][r] - mreg);   // exp(-huge)=0 for masked
                lsum += p[nb][r];
            }
        lreg += lsum;                        // per-lane partial; folded at end

        // P -> LDS via packed HW convert
#pragma unroll
        for (int nb = 0; nb < 2; ++nb) {
            uint2 pk2;
            pk2.x = cvtpk_bf16(p[nb][0], p[nb][1]);
            pk2.y = cvtpk_bf16(p[nb][2], p[nb][3]);
            *(uint2*)&Pt[w][l15][nb * 16 + quad * 4] = pk2;
        }

        asm volatile("s_waitcnt lgkmcnt(0)" ::: "memory");   // wave-local RAW on Pt[w]
        bfrag pf = *(const bfrag*)&Pt[w][l15][quad * 8];
#pragma unroll
        for (int nb2 = 0; nb2 < 8; ++nb2) {
            bfrag vf = *(const bfrag*)&Vt[cur][nb2 * 16 + l15][quad * 8];
            o[nb2] = __builtin_amdgcn_mfma_f32_16x16x32_bf16(pf, vf, o[nb2], 0, 0, 0);
        }
    }

    // final: fold the deferred per-lane l partials (once per pass), then
    // fetch per-q l via width-16 shfl, divide, packed convert, store
    lreg += __shfl_xor(lreg, 16, 64);
    lreg += __shfl_xor(lreg, 32, 64);
    float lr[4];
#pragma unroll
    for (int r = 0; r < 4; ++r) lr[r] = __shfl(lreg, quad * 4 + r, 16);
#pragma unroll
    for (int nb2 = 0; nb2 < 8; ++nb2) {
        unsigned int lo = cvtpk_bf16(o[nb2][0] / lr[0], o[nb2][1] / lr[1]);
        unsigned int hi = cvtpk_bf16(o[nb2][2] / lr[2], o[nb2][3] / lr[3]);
        unsigned short ov[4] = {(unsigned short)lo, (unsigned short)(lo >> 16),
                                (unsigned short)hi, (unsigned short)(hi >> 16)};
#pragma unroll
        for (int r = 0; r < 4; ++r) {
            int qg = qbase + w * 16 + quad * 4 + r;
            att[(size_t)(b * TT + qg) * 2048 + h * 128 + nb2 * 16 + l15] = ov[r];
        }
    }
}

__global__ __launch_bounds__(512, 4) void k_flash(const unsigned short* __restrict__ QKV,
                                                  const unsigned short* __restrict__ VbT,
                                                  unsigned short* __restrict__ att) {
    __shared__ alignas(16) unsigned short Ks[2][32][136];
    __shared__ alignas(16) unsigned short Vt[2][128][40];
    __shared__ alignas(16) unsigned short Pt[8][16][40];
    int bh = blockIdx.y;
    int b = bh >> 4, h = bh & 15;
    int kvh = h >> 2;
    int i = blockIdx.x;

    flash_pass(i * 128, b, h, kvh, QKV, VbT, att, Ks, Vt, Pt);
    __syncthreads();
    flash_pass((15 - i) * 128, b, h, kvh, QKV, VbT, att, Ks, Vt, Pt);
}

// ---------------------------------------------------------------------------
extern "C" void kernel_launch(void* const* d_in, const int* in_sizes, int n_in,
                              void* d_out, int out_size, void* d_ws, size_t ws_size,
                              hipStream_t stream) {
    const float* x  = (const float*)d_in[0];
    const float* Wq = (const float*)d_in[1];
    const float* Wk = (const float*)d_in[2];
    const float* Wv = (const float*)d_in[3];
    const float* Wo = (const float*)d_in[4];
    const int* pos  = (const int*)d_in[5];

    char* ws = (char*)d_ws;
    unsigned short* xb   = (unsigned short*)(ws + 0);          // 32 MB (8192x2048); reused as att out
    unsigned short* QKV  = (unsigned short*)(ws + 33554432);   // 48 MB (8192x3072)
    unsigned short* VbT  = (unsigned short*)(ws + 83886080);   //  8 MB (512x8192)
    unsigned short* WqT  = (unsigned short*)(ws + 92274688);   //  8 MB (2048x2048)
    unsigned short* WkvT = (unsigned short*)(ws + 100663296);  //  4 MB (1024x2048) -- contiguous with WqT
    unsigned short* WoT  = (unsigned short*)(ws + 104857600);  //  8 MB
    float2*         tab  = (float2*)(ws + 113246208);          //  1 MB rope trig table -> 114.25 MB

    // x convert + trig table + all weight transposes (one launch)
    k_pre<<<11264, 256, 0, stream>>>(x, xb, tab, pos, Wq, Wk, Wv, Wo, WqT, WkvT, WoT);

    // fused Q|K|V projection: rope in epilogue (Q/K cols) + V-transpose to
    // VbT in epilogue (V cols)
    k_gemm2ph<1><<<dim3(24, 64), 256, 0, stream>>>(xb, WqT, QKV, 8192, 3072, 2048, 0, tab, VbT);

    // causal GQA flash attention (shuffle-free common-path softmax) -> xb
    k_flash<<<dim3(8, 64), 512, 0, stream>>>(QKV, VbT, xb);

    // output projection -> fp32 d_out
    k_gemm2ph<0><<<dim3(16, 64), 256, 0, stream>>>(xb, WoT, d_out, 8192, 2048, 2048, 1, nullptr, nullptr);
}